// Round 9
// baseline (190.842 us; speedup 1.0000x reference)
//
#include <hip/hip_runtime.h>

typedef __bf16 bf16;
typedef __bf16 bf16x4 __attribute__((ext_vector_type(4)));
typedef __bf16 bf16x8 __attribute__((ext_vector_type(8)));
typedef float f32x4 __attribute__((ext_vector_type(4)));

#define MFMA16(a, b, c) __builtin_amdgcn_mfma_f32_16x16x32_bf16((a), (b), (c), 0, 0, 0)

__device__ inline float fexp2(float x) {
    float r;
    asm("v_exp_f32 %0, %1" : "=v"(r) : "v"(x));
    return r;
}

// ---------------------------------------------------------------------------
// K1: transpose x [256][4096] f32 -> xt [4096][256] bf16, LDS-tiled 64x64.
// ---------------------------------------------------------------------------
__global__ void k_transpose_x(const float* __restrict__ x, bf16* __restrict__ xt) {
    __shared__ float tile[64][68];
    const int t = threadIdx.x;
    const int c0 = (blockIdx.x & 3) * 64;
    const int n0 = (blockIdx.x >> 2) * 64;
    {
        const int cr = t >> 4, nc = (t & 15) * 4;
#pragma unroll
        for (int i = 0; i < 4; ++i) {
            const float4 v = *(const float4*)(x + (size_t)(c0 + cr + i * 16) * 4096 + n0 + nc);
            tile[cr + i * 16][nc + 0] = v.x;
            tile[cr + i * 16][nc + 1] = v.y;
            tile[cr + i * 16][nc + 2] = v.z;
            tile[cr + i * 16][nc + 3] = v.w;
        }
    }
    __syncthreads();
    const int n = t >> 2, cc = (t & 3) * 16;
    bf16x8 o0, o1;
#pragma unroll
    for (int j = 0; j < 8; ++j) o0[j] = (bf16)tile[cc + j][n];
#pragma unroll
    for (int j = 0; j < 8; ++j) o1[j] = (bf16)tile[cc + 8 + j][n];
    bf16* dst = xt + (size_t)(n0 + n) * 256 + c0 + cc;
    *(bf16x8*)dst = o0;
    *(bf16x8*)(dst + 8) = o1;
}

// ---------------------------------------------------------------------------
// K2: fused weights Wq/Wk/Wv = w2 @ w1  [512][256] bf16, plus wo/wg -> bf16
// ---------------------------------------------------------------------------
__global__ void k_prep_w(const float* __restrict__ wq1, const float* __restrict__ wk1,
                         const float* __restrict__ wv1, const float* __restrict__ wq2,
                         const float* __restrict__ wk2, const float* __restrict__ wv2,
                         const float* __restrict__ wo, const float* __restrict__ wg,
                         bf16* __restrict__ Wq, bf16* __restrict__ Wk, bf16* __restrict__ Wv,
                         bf16* __restrict__ wo_bf, bf16* __restrict__ wg_bf) {
    int t = blockIdx.x * 256 + threadIdx.x;
    if (t < 393216) {                       // 3 * 512 * 256
        int which = t >> 17;
        int rem = t & 131071;
        int o = rem >> 8, c = rem & 255;
        const float* w1 = which == 0 ? wq1 : which == 1 ? wk1 : wv1;
        const float* w2 = which == 0 ? wq2 : which == 1 ? wk2 : wv2;
        float acc = 0.f;
#pragma unroll
        for (int j = 0; j < 32; ++j) acc += w2[o * 32 + j] * w1[j * 256 + c];
        bf16* W = which == 0 ? Wq : which == 1 ? Wk : Wv;
        W[o * 256 + c] = (bf16)acc;
    } else if (t < 524288) {                // wo: 256*512
        int idx = t - 393216;
        wo_bf[idx] = (bf16)wo[idx];
    } else if (t < 589824) {                // wg: 256*256
        int idx = t - 524288;
        wg_bf[idx] = (bf16)wg[idx];
    }
}

// ---------------------------------------------------------------------------
// Generic GEMM-NT: C[i][j] = sum_k A[i][k] * B[j][k].  A:[M][K] B:[N][K] bf16.
// ---------------------------------------------------------------------------
template <int MODE>
__launch_bounds__(256)
__global__ void k_gemm_nt(const bf16* __restrict__ A, const bf16* __restrict__ B,
                          int K, float scale, void* __restrict__ outp,
                          const float* __restrict__ bias, const float* __restrict__ mul) {
    const int lane = threadIdx.x & 63;
    const int w = threadIdx.x >> 6;
    const int i0 = blockIdx.y * 128 + w * 32;
    const int j0 = blockIdx.x * 64;
    const int lrow = lane & 15;
    const int lk = (lane >> 4) * 8;

    f32x4 acc[2][4];
#pragma unroll
    for (int a = 0; a < 2; ++a)
#pragma unroll
        for (int b = 0; b < 4; ++b) acc[a][b] = (f32x4){0.f, 0.f, 0.f, 0.f};

    for (int k0 = 0; k0 < K; k0 += 32) {
        bf16x8 af[2], bfr[4];
#pragma unroll
        for (int qs = 0; qs < 2; ++qs)
            af[qs] = *(const bf16x8*)(A + (size_t)(i0 + qs * 16 + lrow) * K + k0 + lk);
#pragma unroll
        for (int js = 0; js < 4; ++js)
            bfr[js] = *(const bf16x8*)(B + (size_t)(j0 + js * 16 + lrow) * K + k0 + lk);
#pragma unroll
        for (int qs = 0; qs < 2; ++qs)
#pragma unroll
            for (int js = 0; js < 4; ++js)
                acc[qs][js] = MFMA16(af[qs], bfr[js], acc[qs][js]);
    }

    const int rbase = (lane >> 4) * 4;
#pragma unroll
    for (int qs = 0; qs < 2; ++qs)
#pragma unroll
        for (int js = 0; js < 4; ++js)
#pragma unroll
            for (int r = 0; r < 4; ++r) {
                int i = i0 + qs * 16 + rbase + r;
                int j = j0 + js * 16 + lrow;
                float v = acc[qs][js][r];
                if (MODE == 0) {
                    ((bf16*)outp)[(size_t)(j >> 6) * (4096 * 64) + (size_t)i * 64 + (j & 63)] =
                        (bf16)(v * scale);
                } else if (MODE == 1) {
                    ((bf16*)outp)[(size_t)i * 4096 + j] = (bf16)v;
                } else if (MODE == 2) {
                    ((float*)outp)[(size_t)i * 4096 + j] = v + bias[i];
                } else {
                    float g = v + bias[i];
                    float sg = 1.f / (1.f + __expf(-g));
                    ((float*)outp)[(size_t)i * 4096 + j] = mul[(size_t)i * 4096 + j] * sg;
                }
            }
}

// ---------------------------------------------------------------------------
// K4: flash attention, KV-split S=4, static-max softmax (exp2, shift=0).
// EXACT R5 (passing) structure; single delta: lambda params are
// reference-to-array uint4 (&r)[4] so the staging array does NOT decay to a
// pointer (rule #20) -- after inlining, r[0..3] are literal-indexed locals
// and SROA keeps them in VGPRs instead of scratch.
// grid = 1024 (split<<8 | h<<5 | qt), block = 256 (4 waves x 32 q-rows).
// ---------------------------------------------------------------------------
__launch_bounds__(256, 4)
__global__ void k_attn(const bf16* __restrict__ q, const bf16* __restrict__ k,
                       const bf16* __restrict__ vT, bf16* __restrict__ Opart,
                       float* __restrict__ lpart) {
    __shared__ char kvlds[16384];           // K [64 rows][128B] at 0, V at 8192
    __shared__ char plds[4][4096];          // per-wave P [32 rows][128B]
    const int tid = threadIdx.x;
    const int lane = tid & 63;
    const int w = tid >> 6;
    const int split = blockIdx.x >> 8;
    const int h = (blockIdx.x >> 5) & 7;
    const int qt = blockIdx.x & 31;
    const int qbase = qt * 128 + w * 32;
    const int lrow = lane & 15;
    const int g = lane >> 4;
    const int swzr = (lrow & 7) << 4;

    const bf16* qh = q + (size_t)h * 4096 * 64;
    const bf16* kh = k + (size_t)h * 4096 * 64;
    const bf16* vh = vT + (size_t)h * 64 * 4096;
    char* myp = plds[w];
    const char* Kl = kvlds;
    const char* Vl = kvlds + 8192;

    // staging geometry: threads 0-127 stage K (8KB), 128-255 stage V (8KB);
    // each thread owns one 64B half-row (4 x 16B units).
    const int isV = tid >> 7;
    const int srow = (tid & 127) >> 1;
    const int shalf = tid & 1;
    const int swzs = (srow & 7) << 4;
    char* ldst = kvlds + isV * 8192 + srow * 128;

    auto load_tile = [&](int t, uint4 (&r)[4]) {
        const int kb = split * 1024 + t * 64;
        const bf16* p = isV ? (vh + (size_t)srow * 4096 + kb + shalf * 32)
                            : (kh + (size_t)(kb + srow) * 64 + shalf * 32);
#pragma unroll
        for (int u = 0; u < 4; ++u) r[u] = *(const uint4*)(p + u * 8);
    };
    auto write_tile = [&](uint4 (&r)[4]) {
#pragma unroll
        for (int u = 0; u < 4; ++u)
            *(uint4*)(ldst + ((shalf * 64 + u * 16) ^ swzs)) = r[u];
    };

    // Q as B-fragments (col = q-row = lane&15)
    bf16x8 bq[2][2];
#pragma unroll
    for (int qs = 0; qs < 2; ++qs)
#pragma unroll
        for (int ks = 0; ks < 2; ++ks)
            bq[qs][ks] = *(const bf16x8*)(qh + (size_t)(qbase + qs * 16 + lrow) * 64 +
                                          ks * 32 + g * 8);

    f32x4 accO[2][4];
    float lsum[2] = {0.f, 0.f};
#pragma unroll
    for (int qs = 0; qs < 2; ++qs)
#pragma unroll
        for (int ds = 0; ds < 4; ++ds) accO[qs][ds] = (f32x4){0.f, 0.f, 0.f, 0.f};

    auto compute = [&]() {
        // ---- S^T = K Q^T ----
        f32x4 s[2][4];
#pragma unroll
        for (int qs = 0; qs < 2; ++qs)
#pragma unroll
            for (int js = 0; js < 4; ++js) s[qs][js] = (f32x4){0.f, 0.f, 0.f, 0.f};
#pragma unroll
        for (int ks = 0; ks < 2; ++ks) {
            bf16x8 ak[4];
#pragma unroll
            for (int js = 0; js < 4; ++js)
                ak[js] = *(const bf16x8*)(Kl + (js * 16 + lrow) * 128 +
                                          ((ks * 64 + g * 16) ^ swzr));
#pragma unroll
            for (int qs = 0; qs < 2; ++qs)
#pragma unroll
                for (int js = 0; js < 4; ++js)
                    s[qs][js] = MFMA16(ak[js], bq[qs][ks], s[qs][js]);
        }
        // ---- P = exp2(s) -> per-wave LDS; lsum += P ----
#pragma unroll
        for (int qs = 0; qs < 2; ++qs) {
            const int qrow = qs * 16 + lrow;
#pragma unroll
            for (int js = 0; js < 4; ++js) {
                bf16x4 pk;
#pragma unroll
                for (int r = 0; r < 4; ++r) {
                    float e = fexp2(s[qs][js][r]);
                    lsum[qs] += e;
                    pk[r] = (bf16)e;
                }
                *(bf16x4*)(myp + ((qrow * 128 + js * 32 + g * 8) ^ swzr)) = pk;
            }
        }
        // ---- O += P V ----
#pragma unroll
        for (int ks2 = 0; ks2 < 2; ++ks2) {
            bf16x8 ap[2], bv[4];
#pragma unroll
            for (int qs = 0; qs < 2; ++qs)
                ap[qs] = *(const bf16x8*)(myp + (((qs * 16 + lrow) * 128 + ks2 * 64 + g * 16) ^
                                                swzr));
#pragma unroll
            for (int ds = 0; ds < 4; ++ds)
                bv[ds] = *(const bf16x8*)(Vl + (ds * 16 + lrow) * 128 +
                                          ((ks2 * 64 + g * 16) ^ swzr));
#pragma unroll
            for (int qs = 0; qs < 2; ++qs)
#pragma unroll
                for (int ds = 0; ds < 4; ++ds)
                    accO[qs][ds] = MFMA16(ap[qs], bv[ds], accO[qs][ds]);
        }
    };

    // ---- pipelined main loop: 16 tiles, 2 per iteration ----
    uint4 rA[4], rB[4];
    load_tile(0, rA);
    for (int tt = 0; tt < 8; ++tt) {
        write_tile(rA);
        load_tile(2 * tt + 1, rB);
        __syncthreads();
        compute();
        __syncthreads();
        write_tile(rB);
        if (tt < 7) load_tile(2 * tt + 2, rA);
        __syncthreads();
        compute();
        __syncthreads();
    }

    // ---- store partials (unnormalized) ----
#pragma unroll
    for (int qs = 0; qs < 2; ++qs)
#pragma unroll
        for (int ds = 0; ds < 4; ++ds)
#pragma unroll
            for (int r = 0; r < 4; ++r) {
                const int n = qbase + qs * 16 + 4 * g + r;
                Opart[((size_t)split * 4096 + n) * 512 + h * 64 + ds * 16 + lrow] =
                    (bf16)accO[qs][ds][r];
            }
#pragma unroll
    for (int qs = 0; qs < 2; ++qs) {
        float lv = lsum[qs];
        lv += __shfl_xor(lv, 16);
        lv += __shfl_xor(lv, 32);
        if (lane < 16)
            lpart[((size_t)split * 8 + h) * 4096 + qbase + qs * 16 + lane] = lv;
    }
}

// ---------------------------------------------------------------------------
// K5: combine partials -> o_buf bf16 [4096][512]
// ---------------------------------------------------------------------------
__global__ void k_combine(const bf16* __restrict__ Opart, const float* __restrict__ lpart,
                          bf16* __restrict__ o) {
    const int tid = blockIdx.x * 256 + threadIdx.x;   // 262144
    const int n = tid >> 6;
    const int c8 = (tid & 63) * 8;
    const int h = c8 >> 6;
    float acc[8] = {0, 0, 0, 0, 0, 0, 0, 0};
    float l = 0.f;
#pragma unroll
    for (int s = 0; s < 4; ++s) {
        const bf16x8 v = *(const bf16x8*)(Opart + ((size_t)s * 4096 + n) * 512 + c8);
#pragma unroll
        for (int j = 0; j < 8; ++j) acc[j] += (float)v[j];
        l += lpart[((size_t)s * 8 + h) * 4096 + n];
    }
    const float inv = 1.f / l;
    bf16x8 ov;
#pragma unroll
    for (int j = 0; j < 8; ++j) ov[j] = (bf16)(acc[j] * inv);
    *(bf16x8*)(o + (size_t)n * 512 + c8) = ov;
}

// ---------------------------------------------------------------------------
// K6: depthwise 3x3 conv (SAME).
// ---------------------------------------------------------------------------
__global__ void k_dw(const float* __restrict__ y, const float* __restrict__ wdw,
                     const float* __restrict__ bdw, float* __restrict__ dwout,
                     bf16* __restrict__ dwt) {
    int t = blockIdx.x * 256 + threadIdx.x;   // 1M
    int c = t >> 12, n = t & 4095, yy = n >> 6, xx = n & 63;
    float acc = bdw[c];
    const float* yc = y + (size_t)c * 4096;
#pragma unroll
    for (int ky = 0; ky < 3; ++ky) {
        int ry = yy + ky - 1;
        if ((unsigned)ry < 64u) {
#pragma unroll
            for (int kx = 0; kx < 3; ++kx) {
                int rx = xx + kx - 1;
                if ((unsigned)rx < 64u) acc += wdw[c * 9 + ky * 3 + kx] * yc[ry * 64 + rx];
            }
        }
    }
    dwout[t] = acc;
    dwt[n * 256 + c] = (bf16)acc;
}

// ---------------------------------------------------------------------------
extern "C" void kernel_launch(void* const* d_in, const int* in_sizes, int n_in,
                              void* d_out, int out_size, void* d_ws, size_t ws_size,
                              hipStream_t stream) {
    const float* x   = (const float*)d_in[0];
    const float* wq1 = (const float*)d_in[1];
    const float* wk1 = (const float*)d_in[2];
    const float* wv1 = (const float*)d_in[3];
    const float* wq2 = (const float*)d_in[4];
    const float* wk2 = (const float*)d_in[5];
    const float* wv2 = (const float*)d_in[6];
    const float* wo  = (const float*)d_in[7];
    const float* bo  = (const float*)d_in[8];
    const float* wdw = (const float*)d_in[9];
    const float* bdw = (const float*)d_in[10];
    const float* wg  = (const float*)d_in[11];
    const float* bg  = (const float*)d_in[12];

    char* ws = (char*)d_ws;
    size_t off = 0;
    auto alloc = [&](size_t bytes) {
        char* p = ws + off;
        off += (bytes + 255) & ~(size_t)255;
        return p;
    };
    // persistent
    bf16*  q_buf = (bf16*)alloc((size_t)8 * 4096 * 64 * 2);
    bf16*  k_buf = (bf16*)alloc((size_t)8 * 4096 * 64 * 2);
    bf16*  vT    = (bf16*)alloc((size_t)8 * 64 * 4096 * 2);
    bf16*  o_buf = (bf16*)alloc((size_t)4096 * 512 * 2);
    bf16*  wo_bf = (bf16*)alloc((size_t)256 * 512 * 2);
    bf16*  wg_bf = (bf16*)alloc((size_t)256 * 256 * 2);
    // union region (lifetimes disjoint):
    char* U = ws + off;
    bf16*  xbf = (bf16*)U;
    bf16*  Wq  = (bf16*)(U + (size_t)2 * 1024 * 1024);
    bf16*  Wk  = (bf16*)(U + (size_t)2 * 1024 * 1024 + 262144);
    bf16*  Wv  = (bf16*)(U + (size_t)2 * 1024 * 1024 + 524288);
    bf16*  Opart = (bf16*)U;                                   // 16MB
    float* lpart = (float*)(U + (size_t)16 * 1024 * 1024);     // 512KB
    float* ybuf  = (float*)U;
    float* dwout = (float*)(U + (size_t)4 * 1024 * 1024);
    bf16*  dwt   = (bf16*)(U + (size_t)8 * 1024 * 1024);
    (void)ws_size; (void)in_sizes; (void)n_in; (void)out_size;

    const float QSCALE = 0.125f * 1.4426950408889634f;  // fold 1/sqrt(dk) * log2(e)

    k_transpose_x<<<256, 256, 0, stream>>>(x, xbf);
    k_prep_w<<<2304, 256, 0, stream>>>(wq1, wk1, wv1, wq2, wk2, wv2, wo, wg,
                                       Wq, Wk, Wv, wo_bf, wg_bf);
    k_gemm_nt<0><<<dim3(8, 32), 256, 0, stream>>>(xbf, Wq, 256, QSCALE, q_buf, nullptr, nullptr);
    k_gemm_nt<0><<<dim3(8, 32), 256, 0, stream>>>(xbf, Wk, 256, 1.0f, k_buf, nullptr, nullptr);
    k_gemm_nt<1><<<dim3(64, 4), 256, 0, stream>>>(Wv, xbf, 256, 1.0f, vT, nullptr, nullptr);
    k_attn<<<1024, 256, 0, stream>>>(q_buf, k_buf, vT, Opart, lpart);
    k_combine<<<1024, 256, 0, stream>>>(Opart, lpart, o_buf);
    k_gemm_nt<2><<<dim3(64, 2), 256, 0, stream>>>(wo_bf, o_buf, 512, 1.0f, ybuf, bo, nullptr);
    k_dw<<<4096, 256, 0, stream>>>(ybuf, wdw, bdw, dwout, dwt);
    k_gemm_nt<3><<<dim3(64, 2), 256, 0, stream>>>(wg_bf, dwt, 256, 1.0f, d_out, bg, dwout);
}

// Round 10
// 162.088 us; speedup vs baseline: 1.1774x; 1.1774x over previous
//
#include <hip/hip_runtime.h>

typedef __bf16 bf16;
typedef __bf16 bf16x4 __attribute__((ext_vector_type(4)));
typedef __bf16 bf16x8 __attribute__((ext_vector_type(8)));
typedef float f32x4 __attribute__((ext_vector_type(4)));

#define MFMA16(a, b, c) __builtin_amdgcn_mfma_f32_16x16x32_bf16((a), (b), (c), 0, 0, 0)

__device__ inline float fexp2(float x) {
    float r;
    asm("v_exp_f32 %0, %1" : "=v"(r) : "v"(x));
    return r;
}

// ---------------------------------------------------------------------------
// K1: transpose x [256][4096] f32 -> xt [4096][256] bf16, LDS-tiled 64x64.
// ---------------------------------------------------------------------------
__global__ void k_transpose_x(const float* __restrict__ x, bf16* __restrict__ xt) {
    __shared__ float tile[64][68];
    const int t = threadIdx.x;
    const int c0 = (blockIdx.x & 3) * 64;
    const int n0 = (blockIdx.x >> 2) * 64;
    {
        const int cr = t >> 4, nc = (t & 15) * 4;
#pragma unroll
        for (int i = 0; i < 4; ++i) {
            const float4 v = *(const float4*)(x + (size_t)(c0 + cr + i * 16) * 4096 + n0 + nc);
            tile[cr + i * 16][nc + 0] = v.x;
            tile[cr + i * 16][nc + 1] = v.y;
            tile[cr + i * 16][nc + 2] = v.z;
            tile[cr + i * 16][nc + 3] = v.w;
        }
    }
    __syncthreads();
    const int n = t >> 2, cc = (t & 3) * 16;
    bf16x8 o0, o1;
#pragma unroll
    for (int j = 0; j < 8; ++j) o0[j] = (bf16)tile[cc + j][n];
#pragma unroll
    for (int j = 0; j < 8; ++j) o1[j] = (bf16)tile[cc + 8 + j][n];
    bf16* dst = xt + (size_t)(n0 + n) * 256 + c0 + cc;
    *(bf16x8*)dst = o0;
    *(bf16x8*)(dst + 8) = o1;
}

// ---------------------------------------------------------------------------
// K2: fused weights Wq/Wk/Wv = w2 @ w1  [512][256] bf16, plus wo/wg -> bf16
// ---------------------------------------------------------------------------
__global__ void k_prep_w(const float* __restrict__ wq1, const float* __restrict__ wk1,
                         const float* __restrict__ wv1, const float* __restrict__ wq2,
                         const float* __restrict__ wk2, const float* __restrict__ wv2,
                         const float* __restrict__ wo, const float* __restrict__ wg,
                         bf16* __restrict__ Wq, bf16* __restrict__ Wk, bf16* __restrict__ Wv,
                         bf16* __restrict__ wo_bf, bf16* __restrict__ wg_bf) {
    int t = blockIdx.x * 256 + threadIdx.x;
    if (t < 393216) {                       // 3 * 512 * 256
        int which = t >> 17;
        int rem = t & 131071;
        int o = rem >> 8, c = rem & 255;
        const float* w1 = which == 0 ? wq1 : which == 1 ? wk1 : wv1;
        const float* w2 = which == 0 ? wq2 : which == 1 ? wk2 : wv2;
        float acc = 0.f;
#pragma unroll
        for (int j = 0; j < 32; ++j) acc += w2[o * 32 + j] * w1[j * 256 + c];
        bf16* W = which == 0 ? Wq : which == 1 ? Wk : Wv;
        W[o * 256 + c] = (bf16)acc;
    } else if (t < 524288) {                // wo: 256*512
        int idx = t - 393216;
        wo_bf[idx] = (bf16)wo[idx];
    } else if (t < 589824) {                // wg: 256*256
        int idx = t - 524288;
        wg_bf[idx] = (bf16)wg[idx];
    }
}

// ---------------------------------------------------------------------------
// Generic GEMM-NT: C[i][j] = sum_k A[i][k] * B[j][k].  A:[M][K] B:[N][K] bf16.
// ---------------------------------------------------------------------------
template <int MODE>
__launch_bounds__(256)
__global__ void k_gemm_nt(const bf16* __restrict__ A, const bf16* __restrict__ B,
                          int K, float scale, void* __restrict__ outp,
                          const float* __restrict__ bias, const float* __restrict__ mul) {
    const int lane = threadIdx.x & 63;
    const int w = threadIdx.x >> 6;
    const int i0 = blockIdx.y * 128 + w * 32;
    const int j0 = blockIdx.x * 64;
    const int lrow = lane & 15;
    const int lk = (lane >> 4) * 8;

    f32x4 acc[2][4];
#pragma unroll
    for (int a = 0; a < 2; ++a)
#pragma unroll
        for (int b = 0; b < 4; ++b) acc[a][b] = (f32x4){0.f, 0.f, 0.f, 0.f};

    for (int k0 = 0; k0 < K; k0 += 32) {
        bf16x8 af[2], bfr[4];
#pragma unroll
        for (int qs = 0; qs < 2; ++qs)
            af[qs] = *(const bf16x8*)(A + (size_t)(i0 + qs * 16 + lrow) * K + k0 + lk);
#pragma unroll
        for (int js = 0; js < 4; ++js)
            bfr[js] = *(const bf16x8*)(B + (size_t)(j0 + js * 16 + lrow) * K + k0 + lk);
#pragma unroll
        for (int qs = 0; qs < 2; ++qs)
#pragma unroll
            for (int js = 0; js < 4; ++js)
                acc[qs][js] = MFMA16(af[qs], bfr[js], acc[qs][js]);
    }

    const int rbase = (lane >> 4) * 4;
#pragma unroll
    for (int qs = 0; qs < 2; ++qs)
#pragma unroll
        for (int js = 0; js < 4; ++js)
#pragma unroll
            for (int r = 0; r < 4; ++r) {
                int i = i0 + qs * 16 + rbase + r;
                int j = j0 + js * 16 + lrow;
                float v = acc[qs][js][r];
                if (MODE == 0) {
                    ((bf16*)outp)[(size_t)(j >> 6) * (4096 * 64) + (size_t)i * 64 + (j & 63)] =
                        (bf16)(v * scale);
                } else if (MODE == 1) {
                    ((bf16*)outp)[(size_t)i * 4096 + j] = (bf16)v;
                } else if (MODE == 2) {
                    ((float*)outp)[(size_t)i * 4096 + j] = v + bias[i];
                } else {
                    float g = v + bias[i];
                    float sg = 1.f / (1.f + __expf(-g));
                    ((float*)outp)[(size_t)i * 4096 + j] = mul[(size_t)i * 4096 + j] * sg;
                }
            }
}

// ---------------------------------------------------------------------------
// K4: flash attention, KV-split S=4, static-max softmax (exp2, shift=0).
// R9-passing structure.  Single delta vs R9: plain __launch_bounds__(256) --
// the ",4" min-waves hint empirically capped the allocator at 64 VGPRs
// (R1 with plain (256) got 112), forcing accO/s/staging into scratch:
// 310 MB/dispatch of EA write traffic.  Let the allocator use ~150 regs.
// grid = 1024 (split<<8 | h<<5 | qt), block = 256 (4 waves x 32 q-rows).
// ---------------------------------------------------------------------------
__launch_bounds__(256)
__global__ void k_attn(const bf16* __restrict__ q, const bf16* __restrict__ k,
                       const bf16* __restrict__ vT, bf16* __restrict__ Opart,
                       float* __restrict__ lpart) {
    __shared__ char kvlds[16384];           // K [64 rows][128B] at 0, V at 8192
    __shared__ char plds[4][4096];          // per-wave P [32 rows][128B]
    const int tid = threadIdx.x;
    const int lane = tid & 63;
    const int w = tid >> 6;
    const int split = blockIdx.x >> 8;
    const int h = (blockIdx.x >> 5) & 7;
    const int qt = blockIdx.x & 31;
    const int qbase = qt * 128 + w * 32;
    const int lrow = lane & 15;
    const int g = lane >> 4;
    const int swzr = (lrow & 7) << 4;

    const bf16* qh = q + (size_t)h * 4096 * 64;
    const bf16* kh = k + (size_t)h * 4096 * 64;
    const bf16* vh = vT + (size_t)h * 64 * 4096;
    char* myp = plds[w];
    const char* Kl = kvlds;
    const char* Vl = kvlds + 8192;

    // staging geometry: threads 0-127 stage K (8KB), 128-255 stage V (8KB);
    // each thread owns one 64B half-row (4 x 16B units).
    const int isV = tid >> 7;
    const int srow = (tid & 127) >> 1;
    const int shalf = tid & 1;
    const int swzs = (srow & 7) << 4;
    char* ldst = kvlds + isV * 8192 + srow * 128;

    auto load_tile = [&](int t, uint4 (&r)[4]) {
        const int kb = split * 1024 + t * 64;
        const bf16* p = isV ? (vh + (size_t)srow * 4096 + kb + shalf * 32)
                            : (kh + (size_t)(kb + srow) * 64 + shalf * 32);
#pragma unroll
        for (int u = 0; u < 4; ++u) r[u] = *(const uint4*)(p + u * 8);
    };
    auto write_tile = [&](uint4 (&r)[4]) {
#pragma unroll
        for (int u = 0; u < 4; ++u)
            *(uint4*)(ldst + ((shalf * 64 + u * 16) ^ swzs)) = r[u];
    };

    // Q as B-fragments (col = q-row = lane&15)
    bf16x8 bq[2][2];
#pragma unroll
    for (int qs = 0; qs < 2; ++qs)
#pragma unroll
        for (int ks = 0; ks < 2; ++ks)
            bq[qs][ks] = *(const bf16x8*)(qh + (size_t)(qbase + qs * 16 + lrow) * 64 +
                                          ks * 32 + g * 8);

    f32x4 accO[2][4];
    float lsum[2] = {0.f, 0.f};
#pragma unroll
    for (int qs = 0; qs < 2; ++qs)
#pragma unroll
        for (int ds = 0; ds < 4; ++ds) accO[qs][ds] = (f32x4){0.f, 0.f, 0.f, 0.f};

    auto compute = [&]() {
        // ---- S^T = K Q^T ----
        f32x4 s[2][4];
#pragma unroll
        for (int qs = 0; qs < 2; ++qs)
#pragma unroll
            for (int js = 0; js < 4; ++js) s[qs][js] = (f32x4){0.f, 0.f, 0.f, 0.f};
#pragma unroll
        for (int ks = 0; ks < 2; ++ks) {
            bf16x8 ak[4];
#pragma unroll
            for (int js = 0; js < 4; ++js)
                ak[js] = *(const bf16x8*)(Kl + (js * 16 + lrow) * 128 +
                                          ((ks * 64 + g * 16) ^ swzr));
#pragma unroll
            for (int qs = 0; qs < 2; ++qs)
#pragma unroll
                for (int js = 0; js < 4; ++js)
                    s[qs][js] = MFMA16(ak[js], bq[qs][ks], s[qs][js]);
        }
        // ---- P = exp2(s) -> per-wave LDS; lsum += P ----
#pragma unroll
        for (int qs = 0; qs < 2; ++qs) {
            const int qrow = qs * 16 + lrow;
#pragma unroll
            for (int js = 0; js < 4; ++js) {
                bf16x4 pk;
#pragma unroll
                for (int r = 0; r < 4; ++r) {
                    float e = fexp2(s[qs][js][r]);
                    lsum[qs] += e;
                    pk[r] = (bf16)e;
                }
                *(bf16x4*)(myp + ((qrow * 128 + js * 32 + g * 8) ^ swzr)) = pk;
            }
        }
        // ---- O += P V ----
#pragma unroll
        for (int ks2 = 0; ks2 < 2; ++ks2) {
            bf16x8 ap[2], bv[4];
#pragma unroll
            for (int qs = 0; qs < 2; ++qs)
                ap[qs] = *(const bf16x8*)(myp + (((qs * 16 + lrow) * 128 + ks2 * 64 + g * 16) ^
                                                swzr));
#pragma unroll
            for (int ds = 0; ds < 4; ++ds)
                bv[ds] = *(const bf16x8*)(Vl + (ds * 16 + lrow) * 128 +
                                          ((ks2 * 64 + g * 16) ^ swzr));
#pragma unroll
            for (int qs = 0; qs < 2; ++qs)
#pragma unroll
                for (int ds = 0; ds < 4; ++ds)
                    accO[qs][ds] = MFMA16(ap[qs], bv[ds], accO[qs][ds]);
        }
    };

    // ---- pipelined main loop: 16 tiles, 2 per iteration ----
    uint4 rA[4], rB[4];
    load_tile(0, rA);
    for (int tt = 0; tt < 8; ++tt) {
        write_tile(rA);
        load_tile(2 * tt + 1, rB);
        __syncthreads();
        compute();
        __syncthreads();
        write_tile(rB);
        if (tt < 7) load_tile(2 * tt + 2, rA);
        __syncthreads();
        compute();
        __syncthreads();
    }

    // ---- store partials (unnormalized) ----
#pragma unroll
    for (int qs = 0; qs < 2; ++qs)
#pragma unroll
        for (int ds = 0; ds < 4; ++ds)
#pragma unroll
            for (int r = 0; r < 4; ++r) {
                const int n = qbase + qs * 16 + 4 * g + r;
                Opart[((size_t)split * 4096 + n) * 512 + h * 64 + ds * 16 + lrow] =
                    (bf16)accO[qs][ds][r];
            }
#pragma unroll
    for (int qs = 0; qs < 2; ++qs) {
        float lv = lsum[qs];
        lv += __shfl_xor(lv, 16);
        lv += __shfl_xor(lv, 32);
        if (lane < 16)
            lpart[((size_t)split * 8 + h) * 4096 + qbase + qs * 16 + lane] = lv;
    }
}

// ---------------------------------------------------------------------------
// K5: combine partials -> o_buf bf16 [4096][512]
// ---------------------------------------------------------------------------
__global__ void k_combine(const bf16* __restrict__ Opart, const float* __restrict__ lpart,
                          bf16* __restrict__ o) {
    const int tid = blockIdx.x * 256 + threadIdx.x;   // 262144
    const int n = tid >> 6;
    const int c8 = (tid & 63) * 8;
    const int h = c8 >> 6;
    float acc[8] = {0, 0, 0, 0, 0, 0, 0, 0};
    float l = 0.f;
#pragma unroll
    for (int s = 0; s < 4; ++s) {
        const bf16x8 v = *(const bf16x8*)(Opart + ((size_t)s * 4096 + n) * 512 + c8);
#pragma unroll
        for (int j = 0; j < 8; ++j) acc[j] += (float)v[j];
        l += lpart[((size_t)s * 8 + h) * 4096 + n];
    }
    const float inv = 1.f / l;
    bf16x8 ov;
#pragma unroll
    for (int j = 0; j < 8; ++j) ov[j] = (bf16)(acc[j] * inv);
    *(bf16x8*)(o + (size_t)n * 512 + c8) = ov;
}

// ---------------------------------------------------------------------------
// K6: depthwise 3x3 conv (SAME).
// ---------------------------------------------------------------------------
__global__ void k_dw(const float* __restrict__ y, const float* __restrict__ wdw,
                     const float* __restrict__ bdw, float* __restrict__ dwout,
                     bf16* __restrict__ dwt) {
    int t = blockIdx.x * 256 + threadIdx.x;   // 1M
    int c = t >> 12, n = t & 4095, yy = n >> 6, xx = n & 63;
    float acc = bdw[c];
    const float* yc = y + (size_t)c * 4096;
#pragma unroll
    for (int ky = 0; ky < 3; ++ky) {
        int ry = yy + ky - 1;
        if ((unsigned)ry < 64u) {
#pragma unroll
            for (int kx = 0; kx < 3; ++kx) {
                int rx = xx + kx - 1;
                if ((unsigned)rx < 64u) acc += wdw[c * 9 + ky * 3 + kx] * yc[ry * 64 + rx];
            }
        }
    }
    dwout[t] = acc;
    dwt[n * 256 + c] = (bf16)acc;
}

// ---------------------------------------------------------------------------
extern "C" void kernel_launch(void* const* d_in, const int* in_sizes, int n_in,
                              void* d_out, int out_size, void* d_ws, size_t ws_size,
                              hipStream_t stream) {
    const float* x   = (const float*)d_in[0];
    const float* wq1 = (const float*)d_in[1];
    const float* wk1 = (const float*)d_in[2];
    const float* wv1 = (const float*)d_in[3];
    const float* wq2 = (const float*)d_in[4];
    const float* wk2 = (const float*)d_in[5];
    const float* wv2 = (const float*)d_in[6];
    const float* wo  = (const float*)d_in[7];
    const float* bo  = (const float*)d_in[8];
    const float* wdw = (const float*)d_in[9];
    const float* bdw = (const float*)d_in[10];
    const float* wg  = (const float*)d_in[11];
    const float* bg  = (const float*)d_in[12];

    char* ws = (char*)d_ws;
    size_t off = 0;
    auto alloc = [&](size_t bytes) {
        char* p = ws + off;
        off += (bytes + 255) & ~(size_t)255;
        return p;
    };
    // persistent
    bf16*  q_buf = (bf16*)alloc((size_t)8 * 4096 * 64 * 2);
    bf16*  k_buf = (bf16*)alloc((size_t)8 * 4096 * 64 * 2);
    bf16*  vT    = (bf16*)alloc((size_t)8 * 64 * 4096 * 2);
    bf16*  o_buf = (bf16*)alloc((size_t)4096 * 512 * 2);
    bf16*  wo_bf = (bf16*)alloc((size_t)256 * 512 * 2);
    bf16*  wg_bf = (bf16*)alloc((size_t)256 * 256 * 2);
    // union region (lifetimes disjoint):
    char* U = ws + off;
    bf16*  xbf = (bf16*)U;
    bf16*  Wq  = (bf16*)(U + (size_t)2 * 1024 * 1024);
    bf16*  Wk  = (bf16*)(U + (size_t)2 * 1024 * 1024 + 262144);
    bf16*  Wv  = (bf16*)(U + (size_t)2 * 1024 * 1024 + 524288);
    bf16*  Opart = (bf16*)U;                                   // 16MB
    float* lpart = (float*)(U + (size_t)16 * 1024 * 1024);     // 512KB
    float* ybuf  = (float*)U;
    float* dwout = (float*)(U + (size_t)4 * 1024 * 1024);
    bf16*  dwt   = (bf16*)(U + (size_t)8 * 1024 * 1024);
    (void)ws_size; (void)in_sizes; (void)n_in; (void)out_size;

    const float QSCALE = 0.125f * 1.4426950408889634f;  // fold 1/sqrt(dk) * log2(e)

    k_transpose_x<<<256, 256, 0, stream>>>(x, xbf);
    k_prep_w<<<2304, 256, 0, stream>>>(wq1, wk1, wv1, wq2, wk2, wv2, wo, wg,
                                       Wq, Wk, Wv, wo_bf, wg_bf);
    k_gemm_nt<0><<<dim3(8, 32), 256, 0, stream>>>(xbf, Wq, 256, QSCALE, q_buf, nullptr, nullptr);
    k_gemm_nt<0><<<dim3(8, 32), 256, 0, stream>>>(xbf, Wk, 256, 1.0f, k_buf, nullptr, nullptr);
    k_gemm_nt<1><<<dim3(64, 4), 256, 0, stream>>>(Wv, xbf, 256, 1.0f, vT, nullptr, nullptr);
    k_attn<<<1024, 256, 0, stream>>>(q_buf, k_buf, vT, Opart, lpart);
    k_combine<<<1024, 256, 0, stream>>>(Opart, lpart, o_buf);
    k_gemm_nt<2><<<dim3(64, 2), 256, 0, stream>>>(wo_bf, o_buf, 512, 1.0f, ybuf, bo, nullptr);
    k_dw<<<4096, 256, 0, stream>>>(ybuf, wdw, bdw, dwout, dwt);
    k_gemm_nt<3><<<dim3(64, 2), 256, 0, stream>>>(wg_bf, dwt, 256, 1.0f, d_out, bg, dwout);
}

// Round 11
// 160.773 us; speedup vs baseline: 1.1870x; 1.0082x over previous
//
#include <hip/hip_runtime.h>

typedef __bf16 bf16;
typedef __bf16 bf16x4 __attribute__((ext_vector_type(4)));
typedef __bf16 bf16x8 __attribute__((ext_vector_type(8)));
typedef float f32x4 __attribute__((ext_vector_type(4)));

#define MFMA16(a, b, c) __builtin_amdgcn_mfma_f32_16x16x32_bf16((a), (b), (c), 0, 0, 0)

__device__ inline float fexp2(float x) {
    float r;
    asm("v_exp_f32 %0, %1" : "=v"(r) : "v"(x));
    return r;
}

// ---------------------------------------------------------------------------
// K1: transpose x [256][4096] f32 -> xt [4096][256] bf16, LDS-tiled 64x64.
// ---------------------------------------------------------------------------
__global__ void k_transpose_x(const float* __restrict__ x, bf16* __restrict__ xt) {
    __shared__ float tile[64][68];
    const int t = threadIdx.x;
    const int c0 = (blockIdx.x & 3) * 64;
    const int n0 = (blockIdx.x >> 2) * 64;
    {
        const int cr = t >> 4, nc = (t & 15) * 4;
#pragma unroll
        for (int i = 0; i < 4; ++i) {
            const float4 v = *(const float4*)(x + (size_t)(c0 + cr + i * 16) * 4096 + n0 + nc);
            tile[cr + i * 16][nc + 0] = v.x;
            tile[cr + i * 16][nc + 1] = v.y;
            tile[cr + i * 16][nc + 2] = v.z;
            tile[cr + i * 16][nc + 3] = v.w;
        }
    }
    __syncthreads();
    const int n = t >> 2, cc = (t & 3) * 16;
    bf16x8 o0, o1;
#pragma unroll
    for (int j = 0; j < 8; ++j) o0[j] = (bf16)tile[cc + j][n];
#pragma unroll
    for (int j = 0; j < 8; ++j) o1[j] = (bf16)tile[cc + 8 + j][n];
    bf16* dst = xt + (size_t)(n0 + n) * 256 + c0 + cc;
    *(bf16x8*)dst = o0;
    *(bf16x8*)(dst + 8) = o1;
}

// ---------------------------------------------------------------------------
// K2: fused weights Wq/Wk/Wv = w2 @ w1  [512][256] bf16, plus wo/wg -> bf16
// ---------------------------------------------------------------------------
__global__ void k_prep_w(const float* __restrict__ wq1, const float* __restrict__ wk1,
                         const float* __restrict__ wv1, const float* __restrict__ wq2,
                         const float* __restrict__ wk2, const float* __restrict__ wv2,
                         const float* __restrict__ wo, const float* __restrict__ wg,
                         bf16* __restrict__ Wq, bf16* __restrict__ Wk, bf16* __restrict__ Wv,
                         bf16* __restrict__ wo_bf, bf16* __restrict__ wg_bf) {
    int t = blockIdx.x * 256 + threadIdx.x;
    if (t < 393216) {                       // 3 * 512 * 256
        int which = t >> 17;
        int rem = t & 131071;
        int o = rem >> 8, c = rem & 255;
        const float* w1 = which == 0 ? wq1 : which == 1 ? wk1 : wv1;
        const float* w2 = which == 0 ? wq2 : which == 1 ? wk2 : wv2;
        float acc = 0.f;
#pragma unroll
        for (int j = 0; j < 32; ++j) acc += w2[o * 32 + j] * w1[j * 256 + c];
        bf16* W = which == 0 ? Wq : which == 1 ? Wk : Wv;
        W[o * 256 + c] = (bf16)acc;
    } else if (t < 524288) {                // wo: 256*512
        int idx = t - 393216;
        wo_bf[idx] = (bf16)wo[idx];
    } else if (t < 589824) {                // wg: 256*256
        int idx = t - 524288;
        wg_bf[idx] = (bf16)wg[idx];
    }
}

// ---------------------------------------------------------------------------
// Generic GEMM-NT: C[i][j] = sum_k A[i][k] * B[j][k].  A:[M][K] B:[N][K] bf16.
// ---------------------------------------------------------------------------
template <int MODE>
__launch_bounds__(256)
__global__ void k_gemm_nt(const bf16* __restrict__ A, const bf16* __restrict__ B,
                          int K, float scale, void* __restrict__ outp,
                          const float* __restrict__ bias, const float* __restrict__ mul) {
    const int lane = threadIdx.x & 63;
    const int w = threadIdx.x >> 6;
    const int i0 = blockIdx.y * 128 + w * 32;
    const int j0 = blockIdx.x * 64;
    const int lrow = lane & 15;
    const int lk = (lane >> 4) * 8;

    f32x4 acc[2][4];
#pragma unroll
    for (int a = 0; a < 2; ++a)
#pragma unroll
        for (int b = 0; b < 4; ++b) acc[a][b] = (f32x4){0.f, 0.f, 0.f, 0.f};

    for (int k0 = 0; k0 < K; k0 += 32) {
        bf16x8 af[2], bfr[4];
#pragma unroll
        for (int qs = 0; qs < 2; ++qs)
            af[qs] = *(const bf16x8*)(A + (size_t)(i0 + qs * 16 + lrow) * K + k0 + lk);
#pragma unroll
        for (int js = 0; js < 4; ++js)
            bfr[js] = *(const bf16x8*)(B + (size_t)(j0 + js * 16 + lrow) * K + k0 + lk);
#pragma unroll
        for (int qs = 0; qs < 2; ++qs)
#pragma unroll
            for (int js = 0; js < 4; ++js)
                acc[qs][js] = MFMA16(af[qs], bfr[js], acc[qs][js]);
    }

    const int rbase = (lane >> 4) * 4;
#pragma unroll
    for (int qs = 0; qs < 2; ++qs)
#pragma unroll
        for (int js = 0; js < 4; ++js)
#pragma unroll
            for (int r = 0; r < 4; ++r) {
                int i = i0 + qs * 16 + rbase + r;
                int j = j0 + js * 16 + lrow;
                float v = acc[qs][js][r];
                if (MODE == 0) {
                    ((bf16*)outp)[(size_t)(j >> 6) * (4096 * 64) + (size_t)i * 64 + (j & 63)] =
                        (bf16)(v * scale);
                } else if (MODE == 1) {
                    ((bf16*)outp)[(size_t)i * 4096 + j] = (bf16)v;
                } else if (MODE == 2) {
                    ((float*)outp)[(size_t)i * 4096 + j] = v + bias[i];
                } else {
                    float g = v + bias[i];
                    float sg = 1.f / (1.f + __expf(-g));
                    ((float*)outp)[(size_t)i * 4096 + j] = mul[(size_t)i * 4096 + j] * sg;
                }
            }
}

// ---------------------------------------------------------------------------
// K4: flash attention, KV-split S=4, static-max softmax (exp2, shift=0).
// R10 structure with two register-pressure deltas to kill the residual spill
// (R10: VGPR=92, WRITE_SIZE 215MB scratch):
//  (a) per-qs S split: compute S/softmax/P-write/PV for qs=0, then qs=1
//      (s[ ] 32->16 regs; ak/bv become short transients; +8 ds_read/tile)
//  (b) __launch_bounds__(256,2): R3's ",4" empirically capped VGPRs at 64;
//      ",2" doubles the budget to ~128 >= the ~95-115 peak demand.
// grid = 1024 (split<<8 | h<<5 | qt), block = 256 (4 waves x 32 q-rows).
// ---------------------------------------------------------------------------
__launch_bounds__(256, 2)
__global__ void k_attn(const bf16* __restrict__ q, const bf16* __restrict__ k,
                       const bf16* __restrict__ vT, bf16* __restrict__ Opart,
                       float* __restrict__ lpart) {
    __shared__ char kvlds[16384];           // K [64 rows][128B] at 0, V at 8192
    __shared__ char plds[4][4096];          // per-wave P [32 rows][128B]
    const int tid = threadIdx.x;
    const int lane = tid & 63;
    const int w = tid >> 6;
    const int split = blockIdx.x >> 8;
    const int h = (blockIdx.x >> 5) & 7;
    const int qt = blockIdx.x & 31;
    const int qbase = qt * 128 + w * 32;
    const int lrow = lane & 15;
    const int g = lane >> 4;
    const int swzr = (lrow & 7) << 4;

    const bf16* qh = q + (size_t)h * 4096 * 64;
    const bf16* kh = k + (size_t)h * 4096 * 64;
    const bf16* vh = vT + (size_t)h * 64 * 4096;
    char* myp = plds[w];
    const char* Kl = kvlds;
    const char* Vl = kvlds + 8192;

    // staging geometry: threads 0-127 stage K (8KB), 128-255 stage V (8KB);
    // each thread owns one 64B half-row (4 x 16B units).
    const int isV = tid >> 7;
    const int srow = (tid & 127) >> 1;
    const int shalf = tid & 1;
    const int swzs = (srow & 7) << 4;
    char* ldst = kvlds + isV * 8192 + srow * 128;

    auto load_tile = [&](int t, uint4 (&r)[4]) {
        const int kb = split * 1024 + t * 64;
        const bf16* p = isV ? (vh + (size_t)srow * 4096 + kb + shalf * 32)
                            : (kh + (size_t)(kb + srow) * 64 + shalf * 32);
#pragma unroll
        for (int u = 0; u < 4; ++u) r[u] = *(const uint4*)(p + u * 8);
    };
    auto write_tile = [&](uint4 (&r)[4]) {
#pragma unroll
        for (int u = 0; u < 4; ++u)
            *(uint4*)(ldst + ((shalf * 64 + u * 16) ^ swzs)) = r[u];
    };

    // Q as B-fragments (col = q-row = lane&15)
    bf16x8 bq[2][2];
#pragma unroll
    for (int qs = 0; qs < 2; ++qs)
#pragma unroll
        for (int ks = 0; ks < 2; ++ks)
            bq[qs][ks] = *(const bf16x8*)(qh + (size_t)(qbase + qs * 16 + lrow) * 64 +
                                          ks * 32 + g * 8);

    f32x4 accO[2][4];
    float lsum[2] = {0.f, 0.f};
#pragma unroll
    for (int qs = 0; qs < 2; ++qs)
#pragma unroll
        for (int ds = 0; ds < 4; ++ds) accO[qs][ds] = (f32x4){0.f, 0.f, 0.f, 0.f};

    auto compute = [&]() {
#pragma unroll
        for (int qs = 0; qs < 2; ++qs) {
            const int qrow = qs * 16 + lrow;
            // ---- S^T (this qs only): s[js][r] = S[key=js*16+4g+r][q=qrow] ----
            f32x4 s[4];
#pragma unroll
            for (int js = 0; js < 4; ++js) s[js] = (f32x4){0.f, 0.f, 0.f, 0.f};
#pragma unroll
            for (int ks = 0; ks < 2; ++ks) {
                bf16x8 ak[4];
#pragma unroll
                for (int js = 0; js < 4; ++js)
                    ak[js] = *(const bf16x8*)(Kl + (js * 16 + lrow) * 128 +
                                              ((ks * 64 + g * 16) ^ swzr));
#pragma unroll
                for (int js = 0; js < 4; ++js)
                    s[js] = MFMA16(ak[js], bq[qs][ks], s[js]);
            }
            // ---- P = exp2(s) -> per-wave LDS; lsum += P ----
#pragma unroll
            for (int js = 0; js < 4; ++js) {
                bf16x4 pk;
#pragma unroll
                for (int r = 0; r < 4; ++r) {
                    float e = fexp2(s[js][r]);
                    lsum[qs] += e;
                    pk[r] = (bf16)e;
                }
                *(bf16x4*)(myp + ((qrow * 128 + js * 32 + g * 8) ^ swzr)) = pk;
            }
            // ---- O += P V (this qs) ----
#pragma unroll
            for (int ks2 = 0; ks2 < 2; ++ks2) {
                bf16x8 ap = *(const bf16x8*)(myp + ((qrow * 128 + ks2 * 64 + g * 16) ^ swzr));
                bf16x8 bv[4];
#pragma unroll
                for (int ds = 0; ds < 4; ++ds)
                    bv[ds] = *(const bf16x8*)(Vl + (ds * 16 + lrow) * 128 +
                                              ((ks2 * 64 + g * 16) ^ swzr));
#pragma unroll
                for (int ds = 0; ds < 4; ++ds)
                    accO[qs][ds] = MFMA16(ap, bv[ds], accO[qs][ds]);
            }
        }
    };

    // ---- pipelined main loop: 16 tiles, 2 per iteration ----
    uint4 rA[4], rB[4];
    load_tile(0, rA);
    for (int tt = 0; tt < 8; ++tt) {
        write_tile(rA);
        load_tile(2 * tt + 1, rB);
        __syncthreads();
        compute();
        __syncthreads();
        write_tile(rB);
        if (tt < 7) load_tile(2 * tt + 2, rA);
        __syncthreads();
        compute();
        __syncthreads();
    }

    // ---- store partials (unnormalized) ----
#pragma unroll
    for (int qs = 0; qs < 2; ++qs)
#pragma unroll
        for (int ds = 0; ds < 4; ++ds)
#pragma unroll
            for (int r = 0; r < 4; ++r) {
                const int n = qbase + qs * 16 + 4 * g + r;
                Opart[((size_t)split * 4096 + n) * 512 + h * 64 + ds * 16 + lrow] =
                    (bf16)accO[qs][ds][r];
            }
#pragma unroll
    for (int qs = 0; qs < 2; ++qs) {
        float lv = lsum[qs];
        lv += __shfl_xor(lv, 16);
        lv += __shfl_xor(lv, 32);
        if (lane < 16)
            lpart[((size_t)split * 8 + h) * 4096 + qbase + qs * 16 + lane] = lv;
    }
}

// ---------------------------------------------------------------------------
// K5: combine partials -> o_buf bf16 [4096][512]
// ---------------------------------------------------------------------------
__global__ void k_combine(const bf16* __restrict__ Opart, const float* __restrict__ lpart,
                          bf16* __restrict__ o) {
    const int tid = blockIdx.x * 256 + threadIdx.x;   // 262144
    const int n = tid >> 6;
    const int c8 = (tid & 63) * 8;
    const int h = c8 >> 6;
    float acc[8] = {0, 0, 0, 0, 0, 0, 0, 0};
    float l = 0.f;
#pragma unroll
    for (int s = 0; s < 4; ++s) {
        const bf16x8 v = *(const bf16x8*)(Opart + ((size_t)s * 4096 + n) * 512 + c8);
#pragma unroll
        for (int j = 0; j < 8; ++j) acc[j] += (float)v[j];
        l += lpart[((size_t)s * 8 + h) * 4096 + n];
    }
    const float inv = 1.f / l;
    bf16x8 ov;
#pragma unroll
    for (int j = 0; j < 8; ++j) ov[j] = (bf16)(acc[j] * inv);
    *(bf16x8*)(o + (size_t)n * 512 + c8) = ov;
}

// ---------------------------------------------------------------------------
// K6: depthwise 3x3 conv (SAME).
// ---------------------------------------------------------------------------
__global__ void k_dw(const float* __restrict__ y, const float* __restrict__ wdw,
                     const float* __restrict__ bdw, float* __restrict__ dwout,
                     bf16* __restrict__ dwt) {
    int t = blockIdx.x * 256 + threadIdx.x;   // 1M
    int c = t >> 12, n = t & 4095, yy = n >> 6, xx = n & 63;
    float acc = bdw[c];
    const float* yc = y + (size_t)c * 4096;
#pragma unroll
    for (int ky = 0; ky < 3; ++ky) {
        int ry = yy + ky - 1;
        if ((unsigned)ry < 64u) {
#pragma unroll
            for (int kx = 0; kx < 3; ++kx) {
                int rx = xx + kx - 1;
                if ((unsigned)rx < 64u) acc += wdw[c * 9 + ky * 3 + kx] * yc[ry * 64 + rx];
            }
        }
    }
    dwout[t] = acc;
    dwt[n * 256 + c] = (bf16)acc;
}

// ---------------------------------------------------------------------------
extern "C" void kernel_launch(void* const* d_in, const int* in_sizes, int n_in,
                              void* d_out, int out_size, void* d_ws, size_t ws_size,
                              hipStream_t stream) {
    const float* x   = (const float*)d_in[0];
    const float* wq1 = (const float*)d_in[1];
    const float* wk1 = (const float*)d_in[2];
    const float* wv1 = (const float*)d_in[3];
    const float* wq2 = (const float*)d_in[4];
    const float* wk2 = (const float*)d_in[5];
    const float* wv2 = (const float*)d_in[6];
    const float* wo  = (const float*)d_in[7];
    const float* bo  = (const float*)d_in[8];
    const float* wdw = (const float*)d_in[9];
    const float* bdw = (const float*)d_in[10];
    const float* wg  = (const float*)d_in[11];
    const float* bg  = (const float*)d_in[12];

    char* ws = (char*)d_ws;
    size_t off = 0;
    auto alloc = [&](size_t bytes) {
        char* p = ws + off;
        off += (bytes + 255) & ~(size_t)255;
        return p;
    };
    // persistent
    bf16*  q_buf = (bf16*)alloc((size_t)8 * 4096 * 64 * 2);
    bf16*  k_buf = (bf16*)alloc((size_t)8 * 4096 * 64 * 2);
    bf16*  vT    = (bf16*)alloc((size_t)8 * 64 * 4096 * 2);
    bf16*  o_buf = (bf16*)alloc((size_t)4096 * 512 * 2);
    bf16*  wo_bf = (bf16*)alloc((size_t)256 * 512 * 2);
    bf16*  wg_bf = (bf16*)alloc((size_t)256 * 256 * 2);
    // union region (lifetimes disjoint):
    char* U = ws + off;
    bf16*  xbf = (bf16*)U;
    bf16*  Wq  = (bf16*)(U + (size_t)2 * 1024 * 1024);
    bf16*  Wk  = (bf16*)(U + (size_t)2 * 1024 * 1024 + 262144);
    bf16*  Wv  = (bf16*)(U + (size_t)2 * 1024 * 1024 + 524288);
    bf16*  Opart = (bf16*)U;                                   // 16MB
    float* lpart = (float*)(U + (size_t)16 * 1024 * 1024);     // 512KB
    float* ybuf  = (float*)U;
    float* dwout = (float*)(U + (size_t)4 * 1024 * 1024);
    bf16*  dwt   = (bf16*)(U + (size_t)8 * 1024 * 1024);
    (void)ws_size; (void)in_sizes; (void)n_in; (void)out_size;

    const float QSCALE = 0.125f * 1.4426950408889634f;  // fold 1/sqrt(dk) * log2(e)

    k_transpose_x<<<256, 256, 0, stream>>>(x, xbf);
    k_prep_w<<<2304, 256, 0, stream>>>(wq1, wk1, wv1, wq2, wk2, wv2, wo, wg,
                                       Wq, Wk, Wv, wo_bf, wg_bf);
    k_gemm_nt<0><<<dim3(8, 32), 256, 0, stream>>>(xbf, Wq, 256, QSCALE, q_buf, nullptr, nullptr);
    k_gemm_nt<0><<<dim3(8, 32), 256, 0, stream>>>(xbf, Wk, 256, 1.0f, k_buf, nullptr, nullptr);
    k_gemm_nt<1><<<dim3(64, 4), 256, 0, stream>>>(Wv, xbf, 256, 1.0f, vT, nullptr, nullptr);
    k_attn<<<1024, 256, 0, stream>>>(q_buf, k_buf, vT, Opart, lpart);
    k_combine<<<1024, 256, 0, stream>>>(Opart, lpart, o_buf);
    k_gemm_nt<2><<<dim3(64, 2), 256, 0, stream>>>(wo_bf, o_buf, 512, 1.0f, ybuf, bo, nullptr);
    k_dw<<<4096, 256, 0, stream>>>(ybuf, wdw, bdw, dwout, dwt);
    k_gemm_nt<3><<<dim3(64, 2), 256, 0, stream>>>(wg_bf, dwt, 256, 1.0f, d_out, bg, dwout);
}

// Round 12
// 128.148 us; speedup vs baseline: 1.4892x; 1.2546x over previous
//
#include <hip/hip_runtime.h>

typedef __bf16 bf16;
typedef __bf16 bf16x4 __attribute__((ext_vector_type(4)));
typedef __bf16 bf16x8 __attribute__((ext_vector_type(8)));
typedef float f32x4 __attribute__((ext_vector_type(4)));

#define MFMA16(a, b, c) __builtin_amdgcn_mfma_f32_16x16x32_bf16((a), (b), (c), 0, 0, 0)

__device__ inline float fexp2(float x) {
    float r;
    asm("v_exp_f32 %0, %1" : "=v"(r) : "v"(x));
    return r;
}

// ---------------------------------------------------------------------------
// K1: transpose x [256][4096] f32 -> xt [4096][256] bf16, LDS-tiled 64x64.
// ---------------------------------------------------------------------------
__global__ void k_transpose_x(const float* __restrict__ x, bf16* __restrict__ xt) {
    __shared__ float tile[64][68];
    const int t = threadIdx.x;
    const int c0 = (blockIdx.x & 3) * 64;
    const int n0 = (blockIdx.x >> 2) * 64;
    {
        const int cr = t >> 4, nc = (t & 15) * 4;
#pragma unroll
        for (int i = 0; i < 4; ++i) {
            const float4 v = *(const float4*)(x + (size_t)(c0 + cr + i * 16) * 4096 + n0 + nc);
            tile[cr + i * 16][nc + 0] = v.x;
            tile[cr + i * 16][nc + 1] = v.y;
            tile[cr + i * 16][nc + 2] = v.z;
            tile[cr + i * 16][nc + 3] = v.w;
        }
    }
    __syncthreads();
    const int n = t >> 2, cc = (t & 3) * 16;
    bf16x8 o0, o1;
#pragma unroll
    for (int j = 0; j < 8; ++j) o0[j] = (bf16)tile[cc + j][n];
#pragma unroll
    for (int j = 0; j < 8; ++j) o1[j] = (bf16)tile[cc + 8 + j][n];
    bf16* dst = xt + (size_t)(n0 + n) * 256 + c0 + cc;
    *(bf16x8*)dst = o0;
    *(bf16x8*)(dst + 8) = o1;
}

// ---------------------------------------------------------------------------
// K2: fused weights Wq/Wk/Wv = w2 @ w1  [512][256] bf16, plus wo/wg -> bf16
// ---------------------------------------------------------------------------
__global__ void k_prep_w(const float* __restrict__ wq1, const float* __restrict__ wk1,
                         const float* __restrict__ wv1, const float* __restrict__ wq2,
                         const float* __restrict__ wk2, const float* __restrict__ wv2,
                         const float* __restrict__ wo, const float* __restrict__ wg,
                         bf16* __restrict__ Wq, bf16* __restrict__ Wk, bf16* __restrict__ Wv,
                         bf16* __restrict__ wo_bf, bf16* __restrict__ wg_bf) {
    int t = blockIdx.x * 256 + threadIdx.x;
    if (t < 393216) {                       // 3 * 512 * 256
        int which = t >> 17;
        int rem = t & 131071;
        int o = rem >> 8, c = rem & 255;
        const float* w1 = which == 0 ? wq1 : which == 1 ? wk1 : wv1;
        const float* w2 = which == 0 ? wq2 : which == 1 ? wk2 : wv2;
        float acc = 0.f;
#pragma unroll
        for (int j = 0; j < 32; ++j) acc += w2[o * 32 + j] * w1[j * 256 + c];
        bf16* W = which == 0 ? Wq : which == 1 ? Wk : Wv;
        W[o * 256 + c] = (bf16)acc;
    } else if (t < 524288) {                // wo: 256*512
        int idx = t - 393216;
        wo_bf[idx] = (bf16)wo[idx];
    } else if (t < 589824) {                // wg: 256*256
        int idx = t - 524288;
        wg_bf[idx] = (bf16)wg[idx];
    }
}

// ---------------------------------------------------------------------------
// Generic GEMM-NT: C[i][j] = sum_k A[i][k] * B[j][k].  A:[M][K] B:[N][K] bf16.
// ---------------------------------------------------------------------------
template <int MODE>
__launch_bounds__(256)
__global__ void k_gemm_nt(const bf16* __restrict__ A, const bf16* __restrict__ B,
                          int K, float scale, void* __restrict__ outp,
                          const float* __restrict__ bias, const float* __restrict__ mul) {
    const int lane = threadIdx.x & 63;
    const int w = threadIdx.x >> 6;
    const int i0 = blockIdx.y * 128 + w * 32;
    const int j0 = blockIdx.x * 64;
    const int lrow = lane & 15;
    const int lk = (lane >> 4) * 8;

    f32x4 acc[2][4];
#pragma unroll
    for (int a = 0; a < 2; ++a)
#pragma unroll
        for (int b = 0; b < 4; ++b) acc[a][b] = (f32x4){0.f, 0.f, 0.f, 0.f};

    for (int k0 = 0; k0 < K; k0 += 32) {
        bf16x8 af[2], bfr[4];
#pragma unroll
        for (int qs = 0; qs < 2; ++qs)
            af[qs] = *(const bf16x8*)(A + (size_t)(i0 + qs * 16 + lrow) * K + k0 + lk);
#pragma unroll
        for (int js = 0; js < 4; ++js)
            bfr[js] = *(const bf16x8*)(B + (size_t)(j0 + js * 16 + lrow) * K + k0 + lk);
#pragma unroll
        for (int qs = 0; qs < 2; ++qs)
#pragma unroll
            for (int js = 0; js < 4; ++js)
                acc[qs][js] = MFMA16(af[qs], bfr[js], acc[qs][js]);
    }

    const int rbase = (lane >> 4) * 4;
#pragma unroll
    for (int qs = 0; qs < 2; ++qs)
#pragma unroll
        for (int js = 0; js < 4; ++js)
#pragma unroll
            for (int r = 0; r < 4; ++r) {
                int i = i0 + qs * 16 + rbase + r;
                int j = j0 + js * 16 + lrow;
                float v = acc[qs][js][r];
                if (MODE == 0) {
                    ((bf16*)outp)[(size_t)(j >> 6) * (4096 * 64) + (size_t)i * 64 + (j & 63)] =
                        (bf16)(v * scale);
                } else if (MODE == 1) {
                    ((bf16*)outp)[(size_t)i * 4096 + j] = (bf16)v;
                } else if (MODE == 2) {
                    ((float*)outp)[(size_t)i * 4096 + j] = v + bias[i];
                } else {
                    float g = v + bias[i];
                    float sg = 1.f / (1.f + __expf(-g));
                    ((float*)outp)[(size_t)i * 4096 + j] = mul[(size_t)i * 4096 + j] * sg;
                }
            }
}

// ---------------------------------------------------------------------------
// K4: flash attention, KV-split S=4, static-max softmax (exp2, shift=0).
// LAMBDA-FREE rewrite.  Evidence across R1/R3 (no lambdas: clean writes) vs
// R5-R11 (lambdas: ~200MB scratch writes, VGPR pinned at 92 regardless of
// launch bounds) says hipcc fails to inline the multiply-called compute
// lambda; by-ref captures then force locals into addressable scratch.
// Here the pipeline is restructured so the compute body appears ONCE inline:
//   per tile: write staged regs->LDS | prefetch t+1 into same regs |
//             barrier | compute (per-qs split) | barrier
// Single 16KB KV buffer, single 16-reg staging set.  Plain launch_bounds.
// grid = 1024 (split<<8 | h<<5 | qt), block = 256 (4 waves x 32 q-rows).
// ---------------------------------------------------------------------------
__launch_bounds__(256)
__global__ void k_attn(const bf16* __restrict__ q, const bf16* __restrict__ k,
                       const bf16* __restrict__ vT, bf16* __restrict__ Opart,
                       float* __restrict__ lpart) {
    __shared__ char kvlds[16384];           // K [64 rows][128B] at 0, V at 8192
    __shared__ char plds[4][4096];          // per-wave P [32 rows][128B]
    const int tid = threadIdx.x;
    const int lane = tid & 63;
    const int w = tid >> 6;
    const int split = blockIdx.x >> 8;
    const int h = (blockIdx.x >> 5) & 7;
    const int qt = blockIdx.x & 31;
    const int qbase = qt * 128 + w * 32;
    const int lrow = lane & 15;
    const int g = lane >> 4;
    const int swzr = (lrow & 7) << 4;

    const bf16* qh = q + (size_t)h * 4096 * 64;
    const bf16* kh = k + (size_t)h * 4096 * 64;
    const bf16* vh = vT + (size_t)h * 64 * 4096;
    char* myp = plds[w];
    const char* Kl = kvlds;
    const char* Vl = kvlds + 8192;

    // staging geometry: threads 0-127 stage K (8KB), 128-255 stage V (8KB);
    // each thread owns one 64B half-row (4 x 16B units).
    const int isV = tid >> 7;
    const int srow = (tid & 127) >> 1;
    const int shalf = tid & 1;
    const int swzs = (srow & 7) << 4;
    char* ldst = kvlds + isV * 8192 + srow * 128;
    const bf16* sbase = isV ? (vh + (size_t)srow * 4096 + split * 1024 + shalf * 32)
                            : (kh + ((size_t)split * 1024 + srow) * 64 + shalf * 32);
    const size_t sstep = isV ? 64 : 64 * 64;   // elements per tile step

    // Q as B-fragments (col = q-row = lane&15)
    bf16x8 bq[2][2];
#pragma unroll
    for (int qs = 0; qs < 2; ++qs)
#pragma unroll
        for (int ks = 0; ks < 2; ++ks)
            bq[qs][ks] = *(const bf16x8*)(qh + (size_t)(qbase + qs * 16 + lrow) * 64 +
                                          ks * 32 + g * 8);

    f32x4 accO[2][4];
    float lsum[2] = {0.f, 0.f};
#pragma unroll
    for (int qs = 0; qs < 2; ++qs)
#pragma unroll
        for (int ds = 0; ds < 4; ++ds) accO[qs][ds] = (f32x4){0.f, 0.f, 0.f, 0.f};

    // prologue: stage tile 0 into regs
    uint4 r0, r1, r2, r3;
    {
        const bf16* p = sbase;
        r0 = *(const uint4*)(p);
        r1 = *(const uint4*)(p + 8);
        r2 = *(const uint4*)(p + 16);
        r3 = *(const uint4*)(p + 24);
    }

    for (int t = 0; t < 16; ++t) {
        // ---- write staged tile to LDS (XOR-swizzled rows) ----
        *(uint4*)(ldst + ((shalf * 64 + 0) ^ swzs)) = r0;
        *(uint4*)(ldst + ((shalf * 64 + 16) ^ swzs)) = r1;
        *(uint4*)(ldst + ((shalf * 64 + 32) ^ swzs)) = r2;
        *(uint4*)(ldst + ((shalf * 64 + 48) ^ swzs)) = r3;
        // ---- prefetch next tile into the same regs (latency hides under compute) ----
        if (t < 15) {
            const bf16* p = sbase + (size_t)(t + 1) * sstep;
            r0 = *(const uint4*)(p);
            r1 = *(const uint4*)(p + 8);
            r2 = *(const uint4*)(p + 16);
            r3 = *(const uint4*)(p + 24);
        }
        __syncthreads();

        // ---- compute on this KV tile, one qs half at a time ----
#pragma unroll
        for (int qs = 0; qs < 2; ++qs) {
            const int qrow = qs * 16 + lrow;
            // S^T: s[js][r] = S[key = js*16+4g+r][q = qrow]
            f32x4 s[4];
#pragma unroll
            for (int js = 0; js < 4; ++js) s[js] = (f32x4){0.f, 0.f, 0.f, 0.f};
#pragma unroll
            for (int ks = 0; ks < 2; ++ks) {
                bf16x8 ak[4];
#pragma unroll
                for (int js = 0; js < 4; ++js)
                    ak[js] = *(const bf16x8*)(Kl + (js * 16 + lrow) * 128 +
                                              ((ks * 64 + g * 16) ^ swzr));
#pragma unroll
                for (int js = 0; js < 4; ++js)
                    s[js] = MFMA16(ak[js], bq[qs][ks], s[js]);
            }
            // P = exp2(s) -> per-wave LDS; lsum += P
#pragma unroll
            for (int js = 0; js < 4; ++js) {
                bf16x4 pk;
#pragma unroll
                for (int r = 0; r < 4; ++r) {
                    float e = fexp2(s[js][r]);
                    lsum[qs] += e;
                    pk[r] = (bf16)e;
                }
                *(bf16x4*)(myp + ((qrow * 128 + js * 32 + g * 8) ^ swzr)) = pk;
            }
            // O += P V
#pragma unroll
            for (int ks2 = 0; ks2 < 2; ++ks2) {
                bf16x8 ap = *(const bf16x8*)(myp + ((qrow * 128 + ks2 * 64 + g * 16) ^ swzr));
                bf16x8 bv[4];
#pragma unroll
                for (int ds = 0; ds < 4; ++ds)
                    bv[ds] = *(const bf16x8*)(Vl + (ds * 16 + lrow) * 128 +
                                              ((ks2 * 64 + g * 16) ^ swzr));
#pragma unroll
                for (int ds = 0; ds < 4; ++ds)
                    accO[qs][ds] = MFMA16(ap, bv[ds], accO[qs][ds]);
            }
        }
        __syncthreads();   // all waves done with this KV tile before overwrite
    }

    // ---- store partials (unnormalized) ----
#pragma unroll
    for (int qs = 0; qs < 2; ++qs)
#pragma unroll
        for (int ds = 0; ds < 4; ++ds)
#pragma unroll
            for (int r = 0; r < 4; ++r) {
                const int n = qbase + qs * 16 + 4 * g + r;
                Opart[((size_t)split * 4096 + n) * 512 + h * 64 + ds * 16 + lrow] =
                    (bf16)accO[qs][ds][r];
            }
#pragma unroll
    for (int qs = 0; qs < 2; ++qs) {
        float lv = lsum[qs];
        lv += __shfl_xor(lv, 16);
        lv += __shfl_xor(lv, 32);
        if (lane < 16)
            lpart[((size_t)split * 8 + h) * 4096 + qbase + qs * 16 + lane] = lv;
    }
}

// ---------------------------------------------------------------------------
// K5: combine partials -> o_buf bf16 [4096][512]
// ---------------------------------------------------------------------------
__global__ void k_combine(const bf16* __restrict__ Opart, const float* __restrict__ lpart,
                          bf16* __restrict__ o) {
    const int tid = blockIdx.x * 256 + threadIdx.x;   // 262144
    const int n = tid >> 6;
    const int c8 = (tid & 63) * 8;
    const int h = c8 >> 6;
    float acc[8] = {0, 0, 0, 0, 0, 0, 0, 0};
    float l = 0.f;
#pragma unroll
    for (int s = 0; s < 4; ++s) {
        const bf16x8 v = *(const bf16x8*)(Opart + ((size_t)s * 4096 + n) * 512 + c8);
#pragma unroll
        for (int j = 0; j < 8; ++j) acc[j] += (float)v[j];
        l += lpart[((size_t)s * 8 + h) * 4096 + n];
    }
    const float inv = 1.f / l;
    bf16x8 ov;
#pragma unroll
    for (int j = 0; j < 8; ++j) ov[j] = (bf16)(acc[j] * inv);
    *(bf16x8*)(o + (size_t)n * 512 + c8) = ov;
}

// ---------------------------------------------------------------------------
// K6: depthwise 3x3 conv (SAME).
// ---------------------------------------------------------------------------
__global__ void k_dw(const float* __restrict__ y, const float* __restrict__ wdw,
                     const float* __restrict__ bdw, float* __restrict__ dwout,
                     bf16* __restrict__ dwt) {
    int t = blockIdx.x * 256 + threadIdx.x;   // 1M
    int c = t >> 12, n = t & 4095, yy = n >> 6, xx = n & 63;
    float acc = bdw[c];
    const float* yc = y + (size_t)c * 4096;
#pragma unroll
    for (int ky = 0; ky < 3; ++ky) {
        int ry = yy + ky - 1;
        if ((unsigned)ry < 64u) {
#pragma unroll
            for (int kx = 0; kx < 3; ++kx) {
                int rx = xx + kx - 1;
                if ((unsigned)rx < 64u) acc += wdw[c * 9 + ky * 3 + kx] * yc[ry * 64 + rx];
            }
        }
    }
    dwout[t] = acc;
    dwt[n * 256 + c] = (bf16)acc;
}

// ---------------------------------------------------------------------------
extern "C" void kernel_launch(void* const* d_in, const int* in_sizes, int n_in,
                              void* d_out, int out_size, void* d_ws, size_t ws_size,
                              hipStream_t stream) {
    const float* x   = (const float*)d_in[0];
    const float* wq1 = (const float*)d_in[1];
    const float* wk1 = (const float*)d_in[2];
    const float* wv1 = (const float*)d_in[3];
    const float* wq2 = (const float*)d_in[4];
    const float* wk2 = (const float*)d_in[5];
    const float* wv2 = (const float*)d_in[6];
    const float* wo  = (const float*)d_in[7];
    const float* bo  = (const float*)d_in[8];
    const float* wdw = (const float*)d_in[9];
    const float* bdw = (const float*)d_in[10];
    const float* wg  = (const float*)d_in[11];
    const float* bg  = (const float*)d_in[12];

    char* ws = (char*)d_ws;
    size_t off = 0;
    auto alloc = [&](size_t bytes) {
        char* p = ws + off;
        off += (bytes + 255) & ~(size_t)255;
        return p;
    };
    // persistent
    bf16*  q_buf = (bf16*)alloc((size_t)8 * 4096 * 64 * 2);
    bf16*  k_buf = (bf16*)alloc((size_t)8 * 4096 * 64 * 2);
    bf16*  vT    = (bf16*)alloc((size_t)8 * 64 * 4096 * 2);
    bf16*  o_buf = (bf16*)alloc((size_t)4096 * 512 * 2);
    bf16*  wo_bf = (bf16*)alloc((size_t)256 * 512 * 2);
    bf16*  wg_bf = (bf16*)alloc((size_t)256 * 256 * 2);
    // union region (lifetimes disjoint):
    char* U = ws + off;
    bf16*  xbf = (bf16*)U;
    bf16*  Wq  = (bf16*)(U + (size_t)2 * 1024 * 1024);
    bf16*  Wk  = (bf16*)(U + (size_t)2 * 1024 * 1024 + 262144);
    bf16*  Wv  = (bf16*)(U + (size_t)2 * 1024 * 1024 + 524288);
    bf16*  Opart = (bf16*)U;                                   // 16MB
    float* lpart = (float*)(U + (size_t)16 * 1024 * 1024);     // 512KB
    float* ybuf  = (float*)U;
    float* dwout = (float*)(U + (size_t)4 * 1024 * 1024);
    bf16*  dwt   = (bf16*)(U + (size_t)8 * 1024 * 1024);
    (void)ws_size; (void)in_sizes; (void)n_in; (void)out_size;

    const float QSCALE = 0.125f * 1.4426950408889634f;  // fold 1/sqrt(dk) * log2(e)

    k_transpose_x<<<256, 256, 0, stream>>>(x, xbf);
    k_prep_w<<<2304, 256, 0, stream>>>(wq1, wk1, wv1, wq2, wk2, wv2, wo, wg,
                                       Wq, Wk, Wv, wo_bf, wg_bf);
    k_gemm_nt<0><<<dim3(8, 32), 256, 0, stream>>>(xbf, Wq, 256, QSCALE, q_buf, nullptr, nullptr);
    k_gemm_nt<0><<<dim3(8, 32), 256, 0, stream>>>(xbf, Wk, 256, 1.0f, k_buf, nullptr, nullptr);
    k_gemm_nt<1><<<dim3(64, 4), 256, 0, stream>>>(Wv, xbf, 256, 1.0f, vT, nullptr, nullptr);
    k_attn<<<1024, 256, 0, stream>>>(q_buf, k_buf, vT, Opart, lpart);
    k_combine<<<1024, 256, 0, stream>>>(Opart, lpart, o_buf);
    k_gemm_nt<2><<<dim3(64, 2), 256, 0, stream>>>(wo_bf, o_buf, 512, 1.0f, ybuf, bo, nullptr);
    k_dw<<<4096, 256, 0, stream>>>(ybuf, wdw, bdw, dwout, dwt);
    k_gemm_nt<3><<<dim3(64, 2), 256, 0, stream>>>(wg_bf, dwt, 256, 1.0f, d_out, bg, dwout);
}

// Round 13
// 127.046 us; speedup vs baseline: 1.5021x; 1.0087x over previous
//
#include <hip/hip_runtime.h>

typedef __bf16 bf16;
typedef __bf16 bf16x4 __attribute__((ext_vector_type(4)));
typedef __bf16 bf16x8 __attribute__((ext_vector_type(8)));
typedef float f32x4 __attribute__((ext_vector_type(4)));

#define MFMA16(a, b, c) __builtin_amdgcn_mfma_f32_16x16x32_bf16((a), (b), (c), 0, 0, 0)

__device__ inline float fexp2(float x) {
    float r;
    asm("v_exp_f32 %0, %1" : "=v"(r) : "v"(x));
    return r;
}

// ---------------------------------------------------------------------------
// K1: fused pre-pass.  blocks 0-255: transpose x [256][4096] f32 ->
// xt [4096][256] bf16 (LDS-tiled).  blocks 256+: fused weights
// Wq/Wk/Wv = w2 @ w1 [512][256] bf16 + wo/wg -> bf16.
// ---------------------------------------------------------------------------
__global__ void k_pre(const float* __restrict__ x, bf16* __restrict__ xt,
                      const float* __restrict__ wq1, const float* __restrict__ wk1,
                      const float* __restrict__ wv1, const float* __restrict__ wq2,
                      const float* __restrict__ wk2, const float* __restrict__ wv2,
                      const float* __restrict__ wo, const float* __restrict__ wg,
                      bf16* __restrict__ Wq, bf16* __restrict__ Wk, bf16* __restrict__ Wv,
                      bf16* __restrict__ wo_bf, bf16* __restrict__ wg_bf) {
    __shared__ float tile[64][68];
    const int bx = blockIdx.x;
    if (bx < 256) {
        const int t = threadIdx.x;
        const int c0 = (bx & 3) * 64;
        const int n0 = (bx >> 2) * 64;
        {
            const int cr = t >> 4, nc = (t & 15) * 4;
#pragma unroll
            for (int i = 0; i < 4; ++i) {
                const float4 v = *(const float4*)(x + (size_t)(c0 + cr + i * 16) * 4096 + n0 + nc);
                tile[cr + i * 16][nc + 0] = v.x;
                tile[cr + i * 16][nc + 1] = v.y;
                tile[cr + i * 16][nc + 2] = v.z;
                tile[cr + i * 16][nc + 3] = v.w;
            }
        }
        __syncthreads();
        const int n = t >> 2, cc = (t & 3) * 16;
        bf16x8 o0, o1;
#pragma unroll
        for (int j = 0; j < 8; ++j) o0[j] = (bf16)tile[cc + j][n];
#pragma unroll
        for (int j = 0; j < 8; ++j) o1[j] = (bf16)tile[cc + 8 + j][n];
        bf16* dst = xt + (size_t)(n0 + n) * 256 + c0 + cc;
        *(bf16x8*)dst = o0;
        *(bf16x8*)(dst + 8) = o1;
    } else {
        int t = (bx - 256) * 256 + threadIdx.x;
        if (t < 393216) {                       // 3 * 512 * 256
            int which = t >> 17;
            int rem = t & 131071;
            int o = rem >> 8, c = rem & 255;
            const float* w1 = which == 0 ? wq1 : which == 1 ? wk1 : wv1;
            const float* w2 = which == 0 ? wq2 : which == 1 ? wk2 : wv2;
            float acc = 0.f;
#pragma unroll
            for (int j = 0; j < 32; ++j) acc += w2[o * 32 + j] * w1[j * 256 + c];
            bf16* W = which == 0 ? Wq : which == 1 ? Wk : Wv;
            W[o * 256 + c] = (bf16)acc;
        } else if (t < 524288) {                // wo: 256*512
            int idx = t - 393216;
            wo_bf[idx] = (bf16)wo[idx];
        } else if (t < 589824) {                // wg: 256*256
            int idx = t - 524288;
            wg_bf[idx] = (bf16)wg[idx];
        }
    }
}

// ---------------------------------------------------------------------------
// Generic GEMM-NT: C[i][j] = sum_k A[i][k] * B[j][k].  A:[M][K] B:[N][K] bf16.
// ---------------------------------------------------------------------------
template <int MODE>
__launch_bounds__(256)
__global__ void k_gemm_nt(const bf16* __restrict__ A, const bf16* __restrict__ B,
                          int K, float scale, void* __restrict__ outp,
                          const float* __restrict__ bias, const float* __restrict__ mul) {
    const int lane = threadIdx.x & 63;
    const int w = threadIdx.x >> 6;
    const int i0 = blockIdx.y * 128 + w * 32;
    const int j0 = blockIdx.x * 64;
    const int lrow = lane & 15;
    const int lk = (lane >> 4) * 8;

    f32x4 acc[2][4];
#pragma unroll
    for (int a = 0; a < 2; ++a)
#pragma unroll
        for (int b = 0; b < 4; ++b) acc[a][b] = (f32x4){0.f, 0.f, 0.f, 0.f};

    for (int k0 = 0; k0 < K; k0 += 32) {
        bf16x8 af[2], bfr[4];
#pragma unroll
        for (int qs = 0; qs < 2; ++qs)
            af[qs] = *(const bf16x8*)(A + (size_t)(i0 + qs * 16 + lrow) * K + k0 + lk);
#pragma unroll
        for (int js = 0; js < 4; ++js)
            bfr[js] = *(const bf16x8*)(B + (size_t)(j0 + js * 16 + lrow) * K + k0 + lk);
#pragma unroll
        for (int qs = 0; qs < 2; ++qs)
#pragma unroll
            for (int js = 0; js < 4; ++js)
                acc[qs][js] = MFMA16(af[qs], bfr[js], acc[qs][js]);
    }

    const int rbase = (lane >> 4) * 4;
#pragma unroll
    for (int qs = 0; qs < 2; ++qs)
#pragma unroll
        for (int js = 0; js < 4; ++js)
#pragma unroll
            for (int r = 0; r < 4; ++r) {
                int i = i0 + qs * 16 + rbase + r;
                int j = j0 + js * 16 + lrow;
                float v = acc[qs][js][r];
                if (MODE == 0) {
                    ((bf16*)outp)[(size_t)(j >> 6) * (4096 * 64) + (size_t)i * 64 + (j & 63)] =
                        (bf16)(v * scale);
                } else if (MODE == 1) {
                    ((bf16*)outp)[(size_t)i * 4096 + j] = (bf16)v;
                } else if (MODE == 2) {
                    ((float*)outp)[(size_t)i * 4096 + j] = v + bias[i];
                } else {
                    float g = v + bias[i];
                    float sg = 1.f / (1.f + __expf(-g));
                    ((float*)outp)[(size_t)i * 4096 + j] = mul[(size_t)i * 4096 + j] * sg;
                }
            }
}

// ---------------------------------------------------------------------------
// K4: flash attention, KV-split S=4, static-max softmax (exp2, shift=0).
// Lambda-free (R12 structural fix, WRITE clean at 16.9MB).  R13 deltas:
//  (a) KV double-buffer -> ONE barrier per tile (was 2): write staged regs
//      to buf[cur^1] while computing buf[cur]; barrier at iteration end
//      separates write_t(buf[cur^1]) from compute_{t-1} of the same buffer.
//  (b) row-sum l via ones-MFMA (R2-proven C-layout) instead of 32 VALU adds
//      with a serial dependence chain -- moves work to the 24%-idle MFMA pipe.
// grid = 1024 (split<<8 | h<<5 | qt), block = 256 (4 waves x 32 q-rows).
// ---------------------------------------------------------------------------
__launch_bounds__(256)
__global__ void k_attn(const bf16* __restrict__ q, const bf16* __restrict__ k,
                       const bf16* __restrict__ vT, bf16* __restrict__ Opart,
                       float* __restrict__ lpart) {
    __shared__ char kvlds[2][16384];        // per buf: K [64][128B] at 0, V at 8192
    __shared__ char plds[4][4096];          // per-wave P [32 rows][128B]
    const int tid = threadIdx.x;
    const int lane = tid & 63;
    const int w = tid >> 6;
    const int split = blockIdx.x >> 8;
    const int h = (blockIdx.x >> 5) & 7;
    const int qt = blockIdx.x & 31;
    const int qbase = qt * 128 + w * 32;
    const int lrow = lane & 15;
    const int g = lane >> 4;
    const int swzr = (lrow & 7) << 4;

    const bf16* qh = q + (size_t)h * 4096 * 64;
    const bf16* kh = k + (size_t)h * 4096 * 64;
    const bf16* vh = vT + (size_t)h * 64 * 4096;
    char* myp = plds[w];

    // staging geometry: threads 0-127 stage K (8KB), 128-255 stage V (8KB);
    // each thread owns one 64B half-row (4 x 16B units).
    const int isV = tid >> 7;
    const int srow = (tid & 127) >> 1;
    const int shalf = tid & 1;
    const int swzs = (srow & 7) << 4;
    const int ldoff = isV * 8192 + srow * 128;
    const bf16* sbase = isV ? (vh + (size_t)srow * 4096 + split * 1024 + shalf * 32)
                            : (kh + ((size_t)split * 1024 + srow) * 64 + shalf * 32);
    const size_t sstep = isV ? 64 : 64 * 64;   // elements per tile step

    // Q as B-fragments (col = q-row = lane&15)
    bf16x8 bq[2][2];
#pragma unroll
    for (int qs = 0; qs < 2; ++qs)
#pragma unroll
        for (int ks = 0; ks < 2; ++ks)
            bq[qs][ks] = *(const bf16x8*)(qh + (size_t)(qbase + qs * 16 + lrow) * 64 +
                                          ks * 32 + g * 8);

    f32x4 accO[2][4];
    f32x4 l_acc[2];
#pragma unroll
    for (int qs = 0; qs < 2; ++qs) {
#pragma unroll
        for (int ds = 0; ds < 4; ++ds) accO[qs][ds] = (f32x4){0.f, 0.f, 0.f, 0.f};
        l_acc[qs] = (f32x4){0.f, 0.f, 0.f, 0.f};
    }
    bf16x8 ones;
#pragma unroll
    for (int i = 0; i < 8; ++i) ones[i] = (bf16)1.0f;

    // prologue: tile0 -> buf0; prefetch tile1 into regs
    uint4 r0, r1, r2, r3;
    {
        const bf16* p = sbase;
        r0 = *(const uint4*)(p);
        r1 = *(const uint4*)(p + 8);
        r2 = *(const uint4*)(p + 16);
        r3 = *(const uint4*)(p + 24);
    }
    {
        char* d = kvlds[0] + ldoff;
        *(uint4*)(d + ((shalf * 64 + 0) ^ swzs)) = r0;
        *(uint4*)(d + ((shalf * 64 + 16) ^ swzs)) = r1;
        *(uint4*)(d + ((shalf * 64 + 32) ^ swzs)) = r2;
        *(uint4*)(d + ((shalf * 64 + 48) ^ swzs)) = r3;
    }
    {
        const bf16* p = sbase + sstep;
        r0 = *(const uint4*)(p);
        r1 = *(const uint4*)(p + 8);
        r2 = *(const uint4*)(p + 16);
        r3 = *(const uint4*)(p + 24);
    }
    __syncthreads();

    for (int t = 0; t < 16; ++t) {
        const int cur = t & 1;
        // ---- write tile t+1 (in regs) to the other buffer ----
        if (t < 15) {
            char* d = kvlds[cur ^ 1] + ldoff;
            *(uint4*)(d + ((shalf * 64 + 0) ^ swzs)) = r0;
            *(uint4*)(d + ((shalf * 64 + 16) ^ swzs)) = r1;
            *(uint4*)(d + ((shalf * 64 + 32) ^ swzs)) = r2;
            *(uint4*)(d + ((shalf * 64 + 48) ^ swzs)) = r3;
        }
        // ---- prefetch tile t+2 into regs (hides under compute) ----
        if (t < 14) {
            const bf16* p = sbase + (size_t)(t + 2) * sstep;
            r0 = *(const uint4*)(p);
            r1 = *(const uint4*)(p + 8);
            r2 = *(const uint4*)(p + 16);
            r3 = *(const uint4*)(p + 24);
        }
        const char* Kl = kvlds[cur];
        const char* Vl = kvlds[cur] + 8192;

        // ---- compute on buf[cur], one qs half at a time ----
#pragma unroll
        for (int qs = 0; qs < 2; ++qs) {
            const int qrow = qs * 16 + lrow;
            // S^T: s[js][r] = S[key = js*16+4g+r][q = qrow]
            f32x4 s[4];
#pragma unroll
            for (int js = 0; js < 4; ++js) s[js] = (f32x4){0.f, 0.f, 0.f, 0.f};
#pragma unroll
            for (int ks = 0; ks < 2; ++ks) {
                bf16x8 ak[4];
#pragma unroll
                for (int js = 0; js < 4; ++js)
                    ak[js] = *(const bf16x8*)(Kl + (js * 16 + lrow) * 128 +
                                              ((ks * 64 + g * 16) ^ swzr));
#pragma unroll
                for (int js = 0; js < 4; ++js)
                    s[js] = MFMA16(ak[js], bq[qs][ks], s[js]);
            }
            // P = exp2(s) -> per-wave LDS
#pragma unroll
            for (int js = 0; js < 4; ++js) {
                bf16x4 pk;
#pragma unroll
                for (int r = 0; r < 4; ++r) pk[r] = (bf16)fexp2(s[js][r]);
                *(bf16x4*)(myp + ((qrow * 128 + js * 32 + g * 8) ^ swzr)) = pk;
            }
            // O += P V ;  l += P @ ones (MFMA pipe)
#pragma unroll
            for (int ks2 = 0; ks2 < 2; ++ks2) {
                bf16x8 ap = *(const bf16x8*)(myp + ((qrow * 128 + ks2 * 64 + g * 16) ^ swzr));
                bf16x8 bv[4];
#pragma unroll
                for (int ds = 0; ds < 4; ++ds)
                    bv[ds] = *(const bf16x8*)(Vl + (ds * 16 + lrow) * 128 +
                                              ((ks2 * 64 + g * 16) ^ swzr));
#pragma unroll
                for (int ds = 0; ds < 4; ++ds)
                    accO[qs][ds] = MFMA16(ap, bv[ds], accO[qs][ds]);
                l_acc[qs] = MFMA16(ap, ones, l_acc[qs]);
            }
        }
        __syncthreads();   // separates write(buf[cur^1]) from next compute
    }

    // ---- store partials (unnormalized) ----
#pragma unroll
    for (int qs = 0; qs < 2; ++qs)
#pragma unroll
        for (int ds = 0; ds < 4; ++ds)
#pragma unroll
            for (int r = 0; r < 4; ++r) {
                const int n = qbase + qs * 16 + 4 * g + r;
                Opart[((size_t)split * 4096 + n) * 512 + h * 64 + ds * 16 + lrow] =
                    (bf16)accO[qs][ds][r];
            }
    if (lrow == 0) {
#pragma unroll
        for (int qs = 0; qs < 2; ++qs)
#pragma unroll
            for (int r = 0; r < 4; ++r)
                lpart[((size_t)split * 8 + h) * 4096 + qbase + qs * 16 + 4 * g + r] =
                    l_acc[qs][r];
    }
}

// ---------------------------------------------------------------------------
// K5: combine partials -> o_buf bf16 [4096][512]
// ---------------------------------------------------------------------------
__global__ void k_combine(const bf16* __restrict__ Opart, const float* __restrict__ lpart,
                          bf16* __restrict__ o) {
    const int tid = blockIdx.x * 256 + threadIdx.x;   // 262144
    const int n = tid >> 6;
    const int c8 = (tid & 63) * 8;
    const int h = c8 >> 6;
    float acc[8] = {0, 0, 0, 0, 0, 0, 0, 0};
    float l = 0.f;
#pragma unroll
    for (int s = 0; s < 4; ++s) {
        const bf16x8 v = *(const bf16x8*)(Opart + ((size_t)s * 4096 + n) * 512 + c8);
#pragma unroll
        for (int j = 0; j < 8; ++j) acc[j] += (float)v[j];
        l += lpart[((size_t)s * 8 + h) * 4096 + n];
    }
    const float inv = 1.f / l;
    bf16x8 ov;
#pragma unroll
    for (int j = 0; j < 8; ++j) ov[j] = (bf16)(acc[j] * inv);
    *(bf16x8*)(o + (size_t)n * 512 + c8) = ov;
}

// ---------------------------------------------------------------------------
// K6: depthwise 3x3 conv (SAME).
// ---------------------------------------------------------------------------
__global__ void k_dw(const float* __restrict__ y, const float* __restrict__ wdw,
                     const float* __restrict__ bdw, float* __restrict__ dwout,
                     bf16* __restrict__ dwt) {
    int t = blockIdx.x * 256 + threadIdx.x;   // 1M
    int c = t >> 12, n = t & 4095, yy = n >> 6, xx = n & 63;
    float acc = bdw[c];
    const float* yc = y + (size_t)c * 4096;
#pragma unroll
    for (int ky = 0; ky < 3; ++ky) {
        int ry = yy + ky - 1;
        if ((unsigned)ry < 64u) {
#pragma unroll
            for (int kx = 0; kx < 3; ++kx) {
                int rx = xx + kx - 1;
                if ((unsigned)rx < 64u) acc += wdw[c * 9 + ky * 3 + kx] * yc[ry * 64 + rx];
            }
        }
    }
    dwout[t] = acc;
    dwt[n * 256 + c] = (bf16)acc;
}

// ---------------------------------------------------------------------------
extern "C" void kernel_launch(void* const* d_in, const int* in_sizes, int n_in,
                              void* d_out, int out_size, void* d_ws, size_t ws_size,
                              hipStream_t stream) {
    const float* x   = (const float*)d_in[0];
    const float* wq1 = (const float*)d_in[1];
    const float* wk1 = (const float*)d_in[2];
    const float* wv1 = (const float*)d_in[3];
    const float* wq2 = (const float*)d_in[4];
    const float* wk2 = (const float*)d_in[5];
    const float* wv2 = (const float*)d_in[6];
    const float* wo  = (const float*)d_in[7];
    const float* bo  = (const float*)d_in[8];
    const float* wdw = (const float*)d_in[9];
    const float* bdw = (const float*)d_in[10];
    const float* wg  = (const float*)d_in[11];
    const float* bg  = (const float*)d_in[12];

    char* ws = (char*)d_ws;
    size_t off = 0;
    auto alloc = [&](size_t bytes) {
        char* p = ws + off;
        off += (bytes + 255) & ~(size_t)255;
        return p;
    };
    // persistent
    bf16*  q_buf = (bf16*)alloc((size_t)8 * 4096 * 64 * 2);
    bf16*  k_buf = (bf16*)alloc((size_t)8 * 4096 * 64 * 2);
    bf16*  vT    = (bf16*)alloc((size_t)8 * 64 * 4096 * 2);
    bf16*  o_buf = (bf16*)alloc((size_t)4096 * 512 * 2);
    bf16*  wo_bf = (bf16*)alloc((size_t)256 * 512 * 2);
    bf16*  wg_bf = (bf16*)alloc((size_t)256 * 256 * 2);
    // union region (lifetimes disjoint):
    char* U = ws + off;
    bf16*  xbf = (bf16*)U;
    bf16*  Wq  = (bf16*)(U + (size_t)2 * 1024 * 1024);
    bf16*  Wk  = (bf16*)(U + (size_t)2 * 1024 * 1024 + 262144);
    bf16*  Wv  = (bf16*)(U + (size_t)2 * 1024 * 1024 + 524288);
    bf16*  Opart = (bf16*)U;                                   // 16MB
    float* lpart = (float*)(U + (size_t)16 * 1024 * 1024);     // 512KB
    float* ybuf  = (float*)U;
    float* dwout = (float*)(U + (size_t)4 * 1024 * 1024);
    bf16*  dwt   = (bf16*)(U + (size_t)8 * 1024 * 1024);
    (void)ws_size; (void)in_sizes; (void)n_in; (void)out_size;

    const float QSCALE = 0.125f * 1.4426950408889634f;  // fold 1/sqrt(dk) * log2(e)

    k_pre<<<2560, 256, 0, stream>>>(x, xbf, wq1, wk1, wv1, wq2, wk2, wv2, wo, wg,
                                    Wq, Wk, Wv, wo_bf, wg_bf);
    k_gemm_nt<0><<<dim3(8, 32), 256, 0, stream>>>(xbf, Wq, 256, QSCALE, q_buf, nullptr, nullptr);
    k_gemm_nt<0><<<dim3(8, 32), 256, 0, stream>>>(xbf, Wk, 256, 1.0f, k_buf, nullptr, nullptr);
    k_gemm_nt<1><<<dim3(64, 4), 256, 0, stream>>>(Wv, xbf, 256, 1.0f, vT, nullptr, nullptr);
    k_attn<<<1024, 256, 0, stream>>>(q_buf, k_buf, vT, Opart, lpart);
    k_combine<<<1024, 256, 0, stream>>>(Opart, lpart, o_buf);
    k_gemm_nt<2><<<dim3(64, 2), 256, 0, stream>>>(wo_bf, o_buf, 512, 1.0f, ybuf, bo, nullptr);
    k_dw<<<4096, 256, 0, stream>>>(ybuf, wdw, bdw, dwout, dwt);
    k_gemm_nt<3><<<dim3(64, 2), 256, 0, stream>>>(wg_bf, dwt, 256, 1.0f, d_out, bg, dwout);
}

// Round 14
// 121.617 us; speedup vs baseline: 1.5692x; 1.0446x over previous
//
#include <hip/hip_runtime.h>

typedef __bf16 bf16;
typedef __bf16 bf16x4 __attribute__((ext_vector_type(4)));
typedef __bf16 bf16x8 __attribute__((ext_vector_type(8)));
typedef float f32x4 __attribute__((ext_vector_type(4)));

#define MFMA16(a, b, c) __builtin_amdgcn_mfma_f32_16x16x32_bf16((a), (b), (c), 0, 0, 0)

__device__ inline float fexp2(float x) {
    float r;
    asm("v_exp_f32 %0, %1" : "=v"(r) : "v"(x));
    return r;
}

// ---------------------------------------------------------------------------
// K1: fused pre-pass.  blocks 0-255: transpose x [256][4096] f32 ->
// xt [4096][256] bf16 (LDS-tiled).  blocks 256+: fused weights
// Wq/Wk/Wv = w2 @ w1 [512][256] bf16 + wo/wg -> bf16.
// ---------------------------------------------------------------------------
__global__ void k_pre(const float* __restrict__ x, bf16* __restrict__ xt,
                      const float* __restrict__ wq1, const float* __restrict__ wk1,
                      const float* __restrict__ wv1, const float* __restrict__ wq2,
                      const float* __restrict__ wk2, const float* __restrict__ wv2,
                      const float* __restrict__ wo, const float* __restrict__ wg,
                      bf16* __restrict__ Wq, bf16* __restrict__ Wk, bf16* __restrict__ Wv,
                      bf16* __restrict__ wo_bf, bf16* __restrict__ wg_bf) {
    __shared__ float tile[64][68];
    const int bx = blockIdx.x;
    if (bx < 256) {
        const int t = threadIdx.x;
        const int c0 = (bx & 3) * 64;
        const int n0 = (bx >> 2) * 64;
        {
            const int cr = t >> 4, nc = (t & 15) * 4;
#pragma unroll
            for (int i = 0; i < 4; ++i) {
                const float4 v = *(const float4*)(x + (size_t)(c0 + cr + i * 16) * 4096 + n0 + nc);
                tile[cr + i * 16][nc + 0] = v.x;
                tile[cr + i * 16][nc + 1] = v.y;
                tile[cr + i * 16][nc + 2] = v.z;
                tile[cr + i * 16][nc + 3] = v.w;
            }
        }
        __syncthreads();
        const int n = t >> 2, cc = (t & 3) * 16;
        bf16x8 o0, o1;
#pragma unroll
        for (int j = 0; j < 8; ++j) o0[j] = (bf16)tile[cc + j][n];
#pragma unroll
        for (int j = 0; j < 8; ++j) o1[j] = (bf16)tile[cc + 8 + j][n];
        bf16* dst = xt + (size_t)(n0 + n) * 256 + c0 + cc;
        *(bf16x8*)dst = o0;
        *(bf16x8*)(dst + 8) = o1;
    } else {
        int t = (bx - 256) * 256 + threadIdx.x;
        if (t < 393216) {                       // 3 * 512 * 256
            int which = t >> 17;
            int rem = t & 131071;
            int o = rem >> 8, c = rem & 255;
            const float* w1 = which == 0 ? wq1 : which == 1 ? wk1 : wv1;
            const float* w2 = which == 0 ? wq2 : which == 1 ? wk2 : wv2;
            float acc = 0.f;
#pragma unroll
            for (int j = 0; j < 32; ++j) acc += w2[o * 32 + j] * w1[j * 256 + c];
            bf16* W = which == 0 ? Wq : which == 1 ? Wk : Wv;
            W[o * 256 + c] = (bf16)acc;
        } else if (t < 524288) {                // wo: 256*512
            int idx = t - 393216;
            wo_bf[idx] = (bf16)wo[idx];
        } else if (t < 589824) {                // wg: 256*256
            int idx = t - 524288;
            wg_bf[idx] = (bf16)wg[idx];
        }
    }
}

// ---------------------------------------------------------------------------
// GEMM-NT body: C[i][j] = sum_k A[i][k] * B[j][k].  A:[M][K] B:[N][K] bf16.
// MODE 0: -> bf16 [j>>6][i][j&63] with scale; MODE 1: -> bf16 [i][j];
// MODE 2: -> f32 [i][j] + bias[i]; MODE 3: -> f32 mul*sigmoid(acc+bias).
// ---------------------------------------------------------------------------
template <int MODE>
__device__ __forceinline__ void gemm_body(const bf16* __restrict__ A, const bf16* __restrict__ B,
                                          int K, float scale, void* __restrict__ outp,
                                          const float* __restrict__ bias,
                                          const float* __restrict__ mul, int bx, int by) {
    const int lane = threadIdx.x & 63;
    const int w = threadIdx.x >> 6;
    const int i0 = by * 128 + w * 32;
    const int j0 = bx * 64;
    const int lrow = lane & 15;
    const int lk = (lane >> 4) * 8;

    f32x4 acc[2][4];
#pragma unroll
    for (int a = 0; a < 2; ++a)
#pragma unroll
        for (int b = 0; b < 4; ++b) acc[a][b] = (f32x4){0.f, 0.f, 0.f, 0.f};

    for (int k0 = 0; k0 < K; k0 += 32) {
        bf16x8 af[2], bfr[4];
#pragma unroll
        for (int qs = 0; qs < 2; ++qs)
            af[qs] = *(const bf16x8*)(A + (size_t)(i0 + qs * 16 + lrow) * K + k0 + lk);
#pragma unroll
        for (int js = 0; js < 4; ++js)
            bfr[js] = *(const bf16x8*)(B + (size_t)(j0 + js * 16 + lrow) * K + k0 + lk);
#pragma unroll
        for (int qs = 0; qs < 2; ++qs)
#pragma unroll
            for (int js = 0; js < 4; ++js)
                acc[qs][js] = MFMA16(af[qs], bfr[js], acc[qs][js]);
    }

    const int rbase = (lane >> 4) * 4;
#pragma unroll
    for (int qs = 0; qs < 2; ++qs)
#pragma unroll
        for (int js = 0; js < 4; ++js)
#pragma unroll
            for (int r = 0; r < 4; ++r) {
                int i = i0 + qs * 16 + rbase + r;
                int j = j0 + js * 16 + lrow;
                float v = acc[qs][js][r];
                if (MODE == 0) {
                    ((bf16*)outp)[(size_t)(j >> 6) * (4096 * 64) + (size_t)i * 64 + (j & 63)] =
                        (bf16)(v * scale);
                } else if (MODE == 1) {
                    ((bf16*)outp)[(size_t)i * 4096 + j] = (bf16)v;
                } else if (MODE == 2) {
                    ((float*)outp)[(size_t)i * 4096 + j] = v + bias[i];
                } else {
                    float g = v + bias[i];
                    float sg = 1.f / (1.f + __expf(-g));
                    ((float*)outp)[(size_t)i * 4096 + j] = mul[(size_t)i * 4096 + j] * sg;
                }
            }
}

template <int MODE>
__launch_bounds__(256)
__global__ void k_gemm_nt(const bf16* __restrict__ A, const bf16* __restrict__ B,
                          int K, float scale, void* __restrict__ outp,
                          const float* __restrict__ bias, const float* __restrict__ mul) {
    gemm_body<MODE>(A, B, K, scale, outp, bias, mul, blockIdx.x, blockIdx.y);
}

// ---------------------------------------------------------------------------
// K3: merged Q/K/V projection -- one 768-block launch (3x better CU fill than
// three serial 256-block launches).  blocks 0-255: Q (scaled); 256-511: K;
// 512-767: V (transposed output).
// ---------------------------------------------------------------------------
__launch_bounds__(256)
__global__ void k_qkv(const bf16* __restrict__ xbf, const bf16* __restrict__ Wq,
                      const bf16* __restrict__ Wk, const bf16* __restrict__ Wv,
                      bf16* __restrict__ q_buf, bf16* __restrict__ k_buf,
                      bf16* __restrict__ vT, float qscale) {
    const int b = blockIdx.x;
    if (b < 256) {
        gemm_body<0>(xbf, Wq, 256, qscale, q_buf, nullptr, nullptr, b & 7, b >> 3);
    } else if (b < 512) {
        const int bb = b - 256;
        gemm_body<0>(xbf, Wk, 256, 1.0f, k_buf, nullptr, nullptr, bb & 7, bb >> 3);
    } else {
        const int bb = b - 512;
        gemm_body<1>(Wv, xbf, 256, 1.0f, vT, nullptr, nullptr, bb & 63, bb >> 6);
    }
}

// ---------------------------------------------------------------------------
// K4: flash attention, KV-split S=4, static-max softmax (exp2, shift=0).
// R12 proven structure (single 16KB KV buffer, 32KB LDS total, lambda-free,
// reg-staged prefetch of t+1) + ones-MFMA row-sum (R13-validated) +
// s_setprio(1) around the MFMA clusters (T5; cross-block phase diversity).
// grid = 1024 (split<<8 | h<<5 | qt), block = 256 (4 waves x 32 q-rows).
// ---------------------------------------------------------------------------
__launch_bounds__(256)
__global__ void k_attn(const bf16* __restrict__ q, const bf16* __restrict__ k,
                       const bf16* __restrict__ vT, bf16* __restrict__ Opart,
                       float* __restrict__ lpart) {
    __shared__ char kvlds[16384];           // K [64 rows][128B] at 0, V at 8192
    __shared__ char plds[4][4096];          // per-wave P [32 rows][128B]
    const int tid = threadIdx.x;
    const int lane = tid & 63;
    const int w = tid >> 6;
    const int split = blockIdx.x >> 8;
    const int h = (blockIdx.x >> 5) & 7;
    const int qt = blockIdx.x & 31;
    const int qbase = qt * 128 + w * 32;
    const int lrow = lane & 15;
    const int g = lane >> 4;
    const int swzr = (lrow & 7) << 4;

    const bf16* qh = q + (size_t)h * 4096 * 64;
    const bf16* kh = k + (size_t)h * 4096 * 64;
    const bf16* vh = vT + (size_t)h * 64 * 4096;
    char* myp = plds[w];
    const char* Kl = kvlds;
    const char* Vl = kvlds + 8192;

    // staging geometry: threads 0-127 stage K (8KB), 128-255 stage V (8KB);
    // each thread owns one 64B half-row (4 x 16B units).
    const int isV = tid >> 7;
    const int srow = (tid & 127) >> 1;
    const int shalf = tid & 1;
    const int swzs = (srow & 7) << 4;
    char* ldst = kvlds + isV * 8192 + srow * 128;
    const bf16* sbase = isV ? (vh + (size_t)srow * 4096 + split * 1024 + shalf * 32)
                            : (kh + ((size_t)split * 1024 + srow) * 64 + shalf * 32);
    const size_t sstep = isV ? 64 : 64 * 64;   // elements per tile step

    // Q as B-fragments (col = q-row = lane&15)
    bf16x8 bq[2][2];
#pragma unroll
    for (int qs = 0; qs < 2; ++qs)
#pragma unroll
        for (int ks = 0; ks < 2; ++ks)
            bq[qs][ks] = *(const bf16x8*)(qh + (size_t)(qbase + qs * 16 + lrow) * 64 +
                                          ks * 32 + g * 8);

    f32x4 accO[2][4];
    f32x4 l_acc[2];
#pragma unroll
    for (int qs = 0; qs < 2; ++qs) {
#pragma unroll
        for (int ds = 0; ds < 4; ++ds) accO[qs][ds] = (f32x4){0.f, 0.f, 0.f, 0.f};
        l_acc[qs] = (f32x4){0.f, 0.f, 0.f, 0.f};
    }
    bf16x8 ones;
#pragma unroll
    for (int i = 0; i < 8; ++i) ones[i] = (bf16)1.0f;

    // prologue: stage tile 0 into regs
    uint4 r0, r1, r2, r3;
    {
        const bf16* p = sbase;
        r0 = *(const uint4*)(p);
        r1 = *(const uint4*)(p + 8);
        r2 = *(const uint4*)(p + 16);
        r3 = *(const uint4*)(p + 24);
    }

    for (int t = 0; t < 16; ++t) {
        // ---- write staged tile to LDS (XOR-swizzled rows) ----
        *(uint4*)(ldst + ((shalf * 64 + 0) ^ swzs)) = r0;
        *(uint4*)(ldst + ((shalf * 64 + 16) ^ swzs)) = r1;
        *(uint4*)(ldst + ((shalf * 64 + 32) ^ swzs)) = r2;
        *(uint4*)(ldst + ((shalf * 64 + 48) ^ swzs)) = r3;
        // ---- prefetch next tile into the same regs ----
        if (t < 15) {
            const bf16* p = sbase + (size_t)(t + 1) * sstep;
            r0 = *(const uint4*)(p);
            r1 = *(const uint4*)(p + 8);
            r2 = *(const uint4*)(p + 16);
            r3 = *(const uint4*)(p + 24);
        }
        __syncthreads();

        // ---- compute on this KV tile, one qs half at a time ----
#pragma unroll
        for (int qs = 0; qs < 2; ++qs) {
            const int qrow = qs * 16 + lrow;
            // S^T: s[js][r] = S[key = js*16+4g+r][q = qrow]
            f32x4 s[4];
#pragma unroll
            for (int js = 0; js < 4; ++js) s[js] = (f32x4){0.f, 0.f, 0.f, 0.f};
            __builtin_amdgcn_s_setprio(1);
#pragma unroll
            for (int ks = 0; ks < 2; ++ks) {
                bf16x8 ak[4];
#pragma unroll
                for (int js = 0; js < 4; ++js)
                    ak[js] = *(const bf16x8*)(Kl + (js * 16 + lrow) * 128 +
                                              ((ks * 64 + g * 16) ^ swzr));
#pragma unroll
                for (int js = 0; js < 4; ++js)
                    s[js] = MFMA16(ak[js], bq[qs][ks], s[js]);
            }
            __builtin_amdgcn_s_setprio(0);
            // P = exp2(s) -> per-wave LDS
#pragma unroll
            for (int js = 0; js < 4; ++js) {
                bf16x4 pk;
#pragma unroll
                for (int r = 0; r < 4; ++r) pk[r] = (bf16)fexp2(s[js][r]);
                *(bf16x4*)(myp + ((qrow * 128 + js * 32 + g * 8) ^ swzr)) = pk;
            }
            // O += P V ;  l += P @ ones (MFMA pipe)
            __builtin_amdgcn_s_setprio(1);
#pragma unroll
            for (int ks2 = 0; ks2 < 2; ++ks2) {
                bf16x8 ap = *(const bf16x8*)(myp + ((qrow * 128 + ks2 * 64 + g * 16) ^ swzr));
                bf16x8 bv[4];
#pragma unroll
                for (int ds = 0; ds < 4; ++ds)
                    bv[ds] = *(const bf16x8*)(Vl + (ds * 16 + lrow) * 128 +
                                              ((ks2 * 64 + g * 16) ^ swzr));
#pragma unroll
                for (int ds = 0; ds < 4; ++ds)
                    accO[qs][ds] = MFMA16(ap, bv[ds], accO[qs][ds]);
                l_acc[qs] = MFMA16(ap, ones, l_acc[qs]);
            }
            __builtin_amdgcn_s_setprio(0);
        }
        __syncthreads();   // all waves done with this KV tile before overwrite
    }

    // ---- store partials (unnormalized) ----
#pragma unroll
    for (int qs = 0; qs < 2; ++qs)
#pragma unroll
        for (int ds = 0; ds < 4; ++ds)
#pragma unroll
            for (int r = 0; r < 4; ++r) {
                const int n = qbase + qs * 16 + 4 * g + r;
                Opart[((size_t)split * 4096 + n) * 512 + h * 64 + ds * 16 + lrow] =
                    (bf16)accO[qs][ds][r];
            }
    if (lrow == 0) {
#pragma unroll
        for (int qs = 0; qs < 2; ++qs)
#pragma unroll
            for (int r = 0; r < 4; ++r)
                lpart[((size_t)split * 8 + h) * 4096 + qbase + qs * 16 + 4 * g + r] =
                    l_acc[qs][r];
    }
}

// ---------------------------------------------------------------------------
// K5: combine partials -> o_buf bf16 [4096][512]
// ---------------------------------------------------------------------------
__global__ void k_combine(const bf16* __restrict__ Opart, const float* __restrict__ lpart,
                          bf16* __restrict__ o) {
    const int tid = blockIdx.x * 256 + threadIdx.x;   // 262144
    const int n = tid >> 6;
    const int c8 = (tid & 63) * 8;
    const int h = c8 >> 6;
    float acc[8] = {0, 0, 0, 0, 0, 0, 0, 0};
    float l = 0.f;
#pragma unroll
    for (int s = 0; s < 4; ++s) {
        const bf16x8 v = *(const bf16x8*)(Opart + ((size_t)s * 4096 + n) * 512 + c8);
#pragma unroll
        for (int j = 0; j < 8; ++j) acc[j] += (float)v[j];
        l += lpart[((size_t)s * 8 + h) * 4096 + n];
    }
    const float inv = 1.f / l;
    bf16x8 ov;
#pragma unroll
    for (int j = 0; j < 8; ++j) ov[j] = (bf16)(acc[j] * inv);
    *(bf16x8*)(o + (size_t)n * 512 + c8) = ov;
}

// ---------------------------------------------------------------------------
// K6: depthwise 3x3 conv (SAME).
// ---------------------------------------------------------------------------
__global__ void k_dw(const float* __restrict__ y, const float* __restrict__ wdw,
                     const float* __restrict__ bdw, float* __restrict__ dwout,
                     bf16* __restrict__ dwt) {
    int t = blockIdx.x * 256 + threadIdx.x;   // 1M
    int c = t >> 12, n = t & 4095, yy = n >> 6, xx = n & 63;
    float acc = bdw[c];
    const float* yc = y + (size_t)c * 4096;
#pragma unroll
    for (int ky = 0; ky < 3; ++ky) {
        int ry = yy + ky - 1;
        if ((unsigned)ry < 64u) {
#pragma unroll
            for (int kx = 0; kx < 3; ++kx) {
                int rx = xx + kx - 1;
                if ((unsigned)rx < 64u) acc += wdw[c * 9 + ky * 3 + kx] * yc[ry * 64 + rx];
            }
        }
    }
    dwout[t] = acc;
    dwt[n * 256 + c] = (bf16)acc;
}

// ---------------------------------------------------------------------------
extern "C" void kernel_launch(void* const* d_in, const int* in_sizes, int n_in,
                              void* d_out, int out_size, void* d_ws, size_t ws_size,
                              hipStream_t stream) {
    const float* x   = (const float*)d_in[0];
    const float* wq1 = (const float*)d_in[1];
    const float* wk1 = (const float*)d_in[2];
    const float* wv1 = (const float*)d_in[3];
    const float* wq2 = (const float*)d_in[4];
    const float* wk2 = (const float*)d_in[5];
    const float* wv2 = (const float*)d_in[6];
    const float* wo  = (const float*)d_in[7];
    const float* bo  = (const float*)d_in[8];
    const float* wdw = (const float*)d_in[9];
    const float* bdw = (const float*)d_in[10];
    const float* wg  = (const float*)d_in[11];
    const float* bg  = (const float*)d_in[12];

    char* ws = (char*)d_ws;
    size_t off = 0;
    auto alloc = [&](size_t bytes) {
        char* p = ws + off;
        off += (bytes + 255) & ~(size_t)255;
        return p;
    };
    // persistent
    bf16*  q_buf = (bf16*)alloc((size_t)8 * 4096 * 64 * 2);
    bf16*  k_buf = (bf16*)alloc((size_t)8 * 4096 * 64 * 2);
    bf16*  vT    = (bf16*)alloc((size_t)8 * 64 * 4096 * 2);
    bf16*  o_buf = (bf16*)alloc((size_t)4096 * 512 * 2);
    bf16*  wo_bf = (bf16*)alloc((size_t)256 * 512 * 2);
    bf16*  wg_bf = (bf16*)alloc((size_t)256 * 256 * 2);
    // union region (lifetimes disjoint):
    char* U = ws + off;
    bf16*  xbf = (bf16*)U;
    bf16*  Wq  = (bf16*)(U + (size_t)2 * 1024 * 1024);
    bf16*  Wk  = (bf16*)(U + (size_t)2 * 1024 * 1024 + 262144);
    bf16*  Wv  = (bf16*)(U + (size_t)2 * 1024 * 1024 + 524288);
    bf16*  Opart = (bf16*)U;                                   // 16MB
    float* lpart = (float*)(U + (size_t)16 * 1024 * 1024);     // 512KB
    float* ybuf  = (float*)U;
    float* dwout = (float*)(U + (size_t)4 * 1024 * 1024);
    bf16*  dwt   = (bf16*)(U + (size_t)8 * 1024 * 1024);
    (void)ws_size; (void)in_sizes; (void)n_in; (void)out_size;

    const float QSCALE = 0.125f * 1.4426950408889634f;  // fold 1/sqrt(dk) * log2(e)

    k_pre<<<2560, 256, 0, stream>>>(x, xbf, wq1, wk1, wv1, wq2, wk2, wv2, wo, wg,
                                    Wq, Wk, Wv, wo_bf, wg_bf);
    k_qkv<<<768, 256, 0, stream>>>(xbf, Wq, Wk, Wv, q_buf, k_buf, vT, QSCALE);
    k_attn<<<1024, 256, 0, stream>>>(q_buf, k_buf, vT, Opart, lpart);
    k_combine<<<1024, 256, 0, stream>>>(Opart, lpart, o_buf);
    k_gemm_nt<2><<<dim3(64, 2), 256, 0, stream>>>(wo_bf, o_buf, 512, 1.0f, ybuf, bo, nullptr);
    k_dw<<<4096, 256, 0, stream>>>(ybuf, wdw, bdw, dwout, dwt);
    k_gemm_nt<3><<<dim3(64, 2), 256, 0, stream>>>(wg_bf, dwt, 256, 1.0f, d_out, bg, dwout);
}

// Round 15
// 114.551 us; speedup vs baseline: 1.6660x; 1.0617x over previous
//
#include <hip/hip_runtime.h>

typedef __bf16 bf16;
typedef __bf16 bf16x4 __attribute__((ext_vector_type(4)));
typedef __bf16 bf16x8 __attribute__((ext_vector_type(8)));
typedef float f32x4 __attribute__((ext_vector_type(4)));

#define MFMA16(a, b, c) __builtin_amdgcn_mfma_f32_16x16x32_bf16((a), (b), (c), 0, 0, 0)

__device__ inline float fexp2(float x) {
    float r;
    asm("v_exp_f32 %0, %1" : "=v"(r) : "v"(x));
    return r;
}

// ---------------------------------------------------------------------------
// K1: fused pre-pass.  blocks 0-255: transpose x [256][4096] f32 ->
// xt [4096][256] bf16 (LDS-tiled).  blocks 256+: fused weights
// Wq/Wk/Wv = w2 @ w1 [512][256] bf16 + wo/wg -> bf16.
// ---------------------------------------------------------------------------
__global__ void k_pre(const float* __restrict__ x, bf16* __restrict__ xt,
                      const float* __restrict__ wq1, const float* __restrict__ wk1,
                      const float* __restrict__ wv1, const float* __restrict__ wq2,
                      const float* __restrict__ wk2, const float* __restrict__ wv2,
                      const float* __restrict__ wo, const float* __restrict__ wg,
                      bf16* __restrict__ Wq, bf16* __restrict__ Wk, bf16* __restrict__ Wv,
                      bf16* __restrict__ wo_bf, bf16* __restrict__ wg_bf) {
    __shared__ float tile[64][68];
    const int bx = blockIdx.x;
    if (bx < 256) {
        const int t = threadIdx.x;
        const int c0 = (bx & 3) * 64;
        const int n0 = (bx >> 2) * 64;
        {
            const int cr = t >> 4, nc = (t & 15) * 4;
#pragma unroll
            for (int i = 0; i < 4; ++i) {
                const float4 v = *(const float4*)(x + (size_t)(c0 + cr + i * 16) * 4096 + n0 + nc);
                tile[cr + i * 16][nc + 0] = v.x;
                tile[cr + i * 16][nc + 1] = v.y;
                tile[cr + i * 16][nc + 2] = v.z;
                tile[cr + i * 16][nc + 3] = v.w;
            }
        }
        __syncthreads();
        const int n = t >> 2, cc = (t & 3) * 16;
        bf16x8 o0, o1;
#pragma unroll
        for (int j = 0; j < 8; ++j) o0[j] = (bf16)tile[cc + j][n];
#pragma unroll
        for (int j = 0; j < 8; ++j) o1[j] = (bf16)tile[cc + 8 + j][n];
        bf16* dst = xt + (size_t)(n0 + n) * 256 + c0 + cc;
        *(bf16x8*)dst = o0;
        *(bf16x8*)(dst + 8) = o1;
    } else {
        int t = (bx - 256) * 256 + threadIdx.x;
        if (t < 393216) {                       // 3 * 512 * 256
            int which = t >> 17;
            int rem = t & 131071;
            int o = rem >> 8, c = rem & 255;
            const float* w1 = which == 0 ? wq1 : which == 1 ? wk1 : wv1;
            const float* w2 = which == 0 ? wq2 : which == 1 ? wk2 : wv2;
            float acc = 0.f;
#pragma unroll
            for (int j = 0; j < 32; ++j) acc += w2[o * 32 + j] * w1[j * 256 + c];
            bf16* W = which == 0 ? Wq : which == 1 ? Wk : Wv;
            W[o * 256 + c] = (bf16)acc;
        } else if (t < 524288) {                // wo: 256*512
            int idx = t - 393216;
            wo_bf[idx] = (bf16)wo[idx];
        } else if (t < 589824) {                // wg: 256*256
            int idx = t - 524288;
            wg_bf[idx] = (bf16)wg[idx];
        }
    }
}

// ---------------------------------------------------------------------------
// GEMM-NT body (tile 128x64): C[i][j] = sum_k A[i][k]*B[j][k].
// MODE 0: -> bf16 [j>>6][i][j&63] with scale; MODE 1: -> bf16 [i][j].
// ---------------------------------------------------------------------------
template <int MODE>
__device__ __forceinline__ void gemm_body(const bf16* __restrict__ A, const bf16* __restrict__ B,
                                          int K, float scale, void* __restrict__ outp,
                                          int bx, int by) {
    const int lane = threadIdx.x & 63;
    const int w = threadIdx.x >> 6;
    const int i0 = by * 128 + w * 32;
    const int j0 = bx * 64;
    const int lrow = lane & 15;
    const int lk = (lane >> 4) * 8;

    f32x4 acc[2][4];
#pragma unroll
    for (int a = 0; a < 2; ++a)
#pragma unroll
        for (int b = 0; b < 4; ++b) acc[a][b] = (f32x4){0.f, 0.f, 0.f, 0.f};

    for (int k0 = 0; k0 < K; k0 += 32) {
        bf16x8 af[2], bfr[4];
#pragma unroll
        for (int qs = 0; qs < 2; ++qs)
            af[qs] = *(const bf16x8*)(A + (size_t)(i0 + qs * 16 + lrow) * K + k0 + lk);
#pragma unroll
        for (int js = 0; js < 4; ++js)
            bfr[js] = *(const bf16x8*)(B + (size_t)(j0 + js * 16 + lrow) * K + k0 + lk);
#pragma unroll
        for (int qs = 0; qs < 2; ++qs)
#pragma unroll
            for (int js = 0; js < 4; ++js)
                acc[qs][js] = MFMA16(af[qs], bfr[js], acc[qs][js]);
    }

    const int rbase = (lane >> 4) * 4;
#pragma unroll
    for (int qs = 0; qs < 2; ++qs)
#pragma unroll
        for (int js = 0; js < 4; ++js)
#pragma unroll
            for (int r = 0; r < 4; ++r) {
                int i = i0 + qs * 16 + rbase + r;
                int j = j0 + js * 16 + lrow;
                float v = acc[qs][js][r];
                if (MODE == 0) {
                    ((bf16*)outp)[(size_t)(j >> 6) * (4096 * 64) + (size_t)i * 64 + (j & 63)] =
                        (bf16)(v * scale);
                } else {
                    ((bf16*)outp)[(size_t)i * 4096 + j] = (bf16)v;
                }
            }
}

// ---------------------------------------------------------------------------
// GEMM-NT body (tile 64x64, 256-block fill for small outputs):
// MODE 2: -> f32 [i][j] + bias[i]; MODE 3: -> f32 mul*sigmoid(acc+bias).
// ---------------------------------------------------------------------------
template <int MODE>
__launch_bounds__(256)
__global__ void k_gemm64(const bf16* __restrict__ A, const bf16* __restrict__ B,
                         int K, void* __restrict__ outp,
                         const float* __restrict__ bias, const float* __restrict__ mul) {
    const int lane = threadIdx.x & 63;
    const int w = threadIdx.x >> 6;
    const int i0 = blockIdx.y * 64 + w * 16;
    const int j0 = blockIdx.x * 64;
    const int lrow = lane & 15;
    const int lk = (lane >> 4) * 8;

    f32x4 acc[4];
#pragma unroll
    for (int b = 0; b < 4; ++b) acc[b] = (f32x4){0.f, 0.f, 0.f, 0.f};

    for (int k0 = 0; k0 < K; k0 += 32) {
        bf16x8 af = *(const bf16x8*)(A + (size_t)(i0 + lrow) * K + k0 + lk);
        bf16x8 bfr[4];
#pragma unroll
        for (int js = 0; js < 4; ++js)
            bfr[js] = *(const bf16x8*)(B + (size_t)(j0 + js * 16 + lrow) * K + k0 + lk);
#pragma unroll
        for (int js = 0; js < 4; ++js)
            acc[js] = MFMA16(af, bfr[js], acc[js]);
    }

    const int rbase = (lane >> 4) * 4;
#pragma unroll
    for (int js = 0; js < 4; ++js)
#pragma unroll
        for (int r = 0; r < 4; ++r) {
            int i = i0 + rbase + r;
            int j = j0 + js * 16 + lrow;
            float v = acc[js][r];
            if (MODE == 2) {
                ((float*)outp)[(size_t)i * 4096 + j] = v + bias[i];
            } else {
                float g2 = v + bias[i];
                float sg = 1.f / (1.f + __expf(-g2));
                ((float*)outp)[(size_t)i * 4096 + j] = mul[(size_t)i * 4096 + j] * sg;
            }
        }
}

// ---------------------------------------------------------------------------
// K3: merged Q/K/V projection -- one 768-block launch.
// blocks 0-255: Q (scaled); 256-511: K; 512-767: V (transposed output).
// ---------------------------------------------------------------------------
__launch_bounds__(256)
__global__ void k_qkv(const bf16* __restrict__ xbf, const bf16* __restrict__ Wq,
                      const bf16* __restrict__ Wk, const bf16* __restrict__ Wv,
                      bf16* __restrict__ q_buf, bf16* __restrict__ k_buf,
                      bf16* __restrict__ vT, float qscale) {
    const int b = blockIdx.x;
    if (b < 256) {
        gemm_body<0>(xbf, Wq, 256, qscale, q_buf, b & 7, b >> 3);
    } else if (b < 512) {
        const int bb = b - 256;
        gemm_body<0>(xbf, Wk, 256, 1.0f, k_buf, bb & 7, bb >> 3);
    } else {
        const int bb = b - 512;
        gemm_body<1>(Wv, xbf, 256, 1.0f, vT, bb & 63, bb >> 6);
    }
}

// ---------------------------------------------------------------------------
// K4: flash attention, KV-split S=4, static-max softmax (exp2, shift=0).
// R15 delta: K and V fragments are read from LDS ONCE and shared across both
// qs halves (R11's per-qs split doubled them).  LDS ds-ops per lane per tile
// drop 44 -> 28; per-CU LDS issue was the measured ~53us floor pinning attn
// at 58us (MfmaUtil 26%, VALU 40%, HBM 12% -- nothing else saturated).
// Lambda-free; s back to [2][4] f32x4 (R12 proved no spill without lambdas).
// grid = 1024 (split<<8 | h<<5 | qt), block = 256 (4 waves x 32 q-rows).
// ---------------------------------------------------------------------------
__launch_bounds__(256)
__global__ void k_attn(const bf16* __restrict__ q, const bf16* __restrict__ k,
                       const bf16* __restrict__ vT, bf16* __restrict__ Opart,
                       float* __restrict__ lpart) {
    __shared__ char kvlds[16384];           // K [64 rows][128B] at 0, V at 8192
    __shared__ char plds[4][4096];          // per-wave P [32 rows][128B]
    const int tid = threadIdx.x;
    const int lane = tid & 63;
    const int w = tid >> 6;
    const int split = blockIdx.x >> 8;
    const int h = (blockIdx.x >> 5) & 7;
    const int qt = blockIdx.x & 31;
    const int qbase = qt * 128 + w * 32;
    const int lrow = lane & 15;
    const int g = lane >> 4;
    const int swzr = (lrow & 7) << 4;       // same for row lrow and row 16+lrow

    const bf16* qh = q + (size_t)h * 4096 * 64;
    const bf16* kh = k + (size_t)h * 4096 * 64;
    const bf16* vh = vT + (size_t)h * 64 * 4096;
    char* myp = plds[w];
    const char* Kl = kvlds;
    const char* Vl = kvlds + 8192;

    // staging geometry: threads 0-127 stage K (8KB), 128-255 stage V (8KB);
    // each thread owns one 64B half-row (4 x 16B units).
    const int isV = tid >> 7;
    const int srow = (tid & 127) >> 1;
    const int shalf = tid & 1;
    const int swzs = (srow & 7) << 4;
    char* ldst = kvlds + isV * 8192 + srow * 128;
    const bf16* sbase = isV ? (vh + (size_t)srow * 4096 + split * 1024 + shalf * 32)
                            : (kh + ((size_t)split * 1024 + srow) * 64 + shalf * 32);
    const size_t sstep = isV ? 64 : 64 * 64;   // elements per tile step

    // Q as B-fragments (col = q-row = lane&15)
    bf16x8 bq[2][2];
#pragma unroll
    for (int qs = 0; qs < 2; ++qs)
#pragma unroll
        for (int ks = 0; ks < 2; ++ks)
            bq[qs][ks] = *(const bf16x8*)(qh + (size_t)(qbase + qs * 16 + lrow) * 64 +
                                          ks * 32 + g * 8);

    f32x4 accO[2][4];
    f32x4 l_acc[2];
#pragma unroll
    for (int qs = 0; qs < 2; ++qs) {
#pragma unroll
        for (int ds = 0; ds < 4; ++ds) accO[qs][ds] = (f32x4){0.f, 0.f, 0.f, 0.f};
        l_acc[qs] = (f32x4){0.f, 0.f, 0.f, 0.f};
    }
    bf16x8 ones;
#pragma unroll
    for (int i = 0; i < 8; ++i) ones[i] = (bf16)1.0f;

    // prologue: stage tile 0 into regs
    uint4 r0, r1, r2, r3;
    {
        const bf16* p = sbase;
        r0 = *(const uint4*)(p);
        r1 = *(const uint4*)(p + 8);
        r2 = *(const uint4*)(p + 16);
        r3 = *(const uint4*)(p + 24);
    }

    for (int t = 0; t < 16; ++t) {
        // ---- write staged tile to LDS (XOR-swizzled rows) ----
        *(uint4*)(ldst + ((shalf * 64 + 0) ^ swzs)) = r0;
        *(uint4*)(ldst + ((shalf * 64 + 16) ^ swzs)) = r1;
        *(uint4*)(ldst + ((shalf * 64 + 32) ^ swzs)) = r2;
        *(uint4*)(ldst + ((shalf * 64 + 48) ^ swzs)) = r3;
        // ---- prefetch next tile into the same regs ----
        if (t < 15) {
            const bf16* p = sbase + (size_t)(t + 1) * sstep;
            r0 = *(const uint4*)(p);
            r1 = *(const uint4*)(p + 8);
            r2 = *(const uint4*)(p + 16);
            r3 = *(const uint4*)(p + 24);
        }
        __syncthreads();

        // ---- S^T for BOTH qs halves; K fragments read once ----
        f32x4 s[2][4];
#pragma unroll
        for (int qs = 0; qs < 2; ++qs)
#pragma unroll
            for (int js = 0; js < 4; ++js) s[qs][js] = (f32x4){0.f, 0.f, 0.f, 0.f};
        __builtin_amdgcn_s_setprio(1);
#pragma unroll
        for (int ks = 0; ks < 2; ++ks) {
            bf16x8 ak[4];
#pragma unroll
            for (int js = 0; js < 4; ++js)
                ak[js] = *(const bf16x8*)(Kl + (js * 16 + lrow) * 128 +
                                          ((ks * 64 + g * 16) ^ swzr));
#pragma unroll
            for (int qs = 0; qs < 2; ++qs)
#pragma unroll
                for (int js = 0; js < 4; ++js)
                    s[qs][js] = MFMA16(ak[js], bq[qs][ks], s[qs][js]);
        }
        __builtin_amdgcn_s_setprio(0);

        // ---- P = exp2(s) -> per-wave LDS (both qs) ----
#pragma unroll
        for (int qs = 0; qs < 2; ++qs) {
            const int qrow = qs * 16 + lrow;
#pragma unroll
            for (int js = 0; js < 4; ++js) {
                bf16x4 pk;
#pragma unroll
                for (int r = 0; r < 4; ++r) pk[r] = (bf16)fexp2(s[qs][js][r]);
                *(bf16x4*)(myp + ((qrow * 128 + js * 32 + g * 8) ^ swzr)) = pk;
            }
        }

        // ---- O += P V ; l += P @ ones.  V fragments read once ----
        __builtin_amdgcn_s_setprio(1);
#pragma unroll
        for (int ks2 = 0; ks2 < 2; ++ks2) {
            bf16x8 bv[4];
#pragma unroll
            for (int ds = 0; ds < 4; ++ds)
                bv[ds] = *(const bf16x8*)(Vl + (ds * 16 + lrow) * 128 +
                                          ((ks2 * 64 + g * 16) ^ swzr));
            bf16x8 ap0 = *(const bf16x8*)(myp + ((lrow * 128 + ks2 * 64 + g * 16) ^ swzr));
            bf16x8 ap1 = *(const bf16x8*)(myp + (((16 + lrow) * 128 + ks2 * 64 + g * 16) ^ swzr));
#pragma unroll
            for (int ds = 0; ds < 4; ++ds)
                accO[0][ds] = MFMA16(ap0, bv[ds], accO[0][ds]);
            l_acc[0] = MFMA16(ap0, ones, l_acc[0]);
#pragma unroll
            for (int ds = 0; ds < 4; ++ds)
                accO[1][ds] = MFMA16(ap1, bv[ds], accO[1][ds]);
            l_acc[1] = MFMA16(ap1, ones, l_acc[1]);
        }
        __builtin_amdgcn_s_setprio(0);
        __syncthreads();   // all waves done with this KV tile before overwrite
    }

    // ---- store partials (unnormalized) ----
#pragma unroll
    for (int qs = 0; qs < 2; ++qs)
#pragma unroll
        for (int ds = 0; ds < 4; ++ds)
#pragma unroll
            for (int r = 0; r < 4; ++r) {
                const int n = qbase + qs * 16 + 4 * g + r;
                Opart[((size_t)split * 4096 + n) * 512 + h * 64 + ds * 16 + lrow] =
                    (bf16)accO[qs][ds][r];
            }
    if (lrow == 0) {
#pragma unroll
        for (int qs = 0; qs < 2; ++qs)
#pragma unroll
            for (int r = 0; r < 4; ++r)
                lpart[((size_t)split * 8 + h) * 4096 + qbase + qs * 16 + 4 * g + r] =
                    l_acc[qs][r];
    }
}

// ---------------------------------------------------------------------------
// K5: combine partials -> o_buf bf16 [4096][512]
// ---------------------------------------------------------------------------
__global__ void k_combine(const bf16* __restrict__ Opart, const float* __restrict__ lpart,
                          bf16* __restrict__ o) {
    const int tid = blockIdx.x * 256 + threadIdx.x;   // 262144
    const int n = tid >> 6;
    const int c8 = (tid & 63) * 8;
    const int h = c8 >> 6;
    float acc[8] = {0, 0, 0, 0, 0, 0, 0, 0};
    float l = 0.f;
#pragma unroll
    for (int s = 0; s < 4; ++s) {
        const bf16x8 v = *(const bf16x8*)(Opart + ((size_t)s * 4096 + n) * 512 + c8);
#pragma unroll
        for (int j = 0; j < 8; ++j) acc[j] += (float)v[j];
        l += lpart[((size_t)s * 8 + h) * 4096 + n];
    }
    const float inv = 1.f / l;
    bf16x8 ov;
#pragma unroll
    for (int j = 0; j < 8; ++j) ov[j] = (bf16)(acc[j] * inv);
    *(bf16x8*)(o + (size_t)n * 512 + c8) = ov;
}

// ---------------------------------------------------------------------------
// K6: depthwise 3x3 conv (SAME).
// ---------------------------------------------------------------------------
__global__ void k_dw(const float* __restrict__ y, const float* __restrict__ wdw,
                     const float* __restrict__ bdw, float* __restrict__ dwout,
                     bf16* __restrict__ dwt) {
    int t = blockIdx.x * 256 + threadIdx.x;   // 1M
    int c = t >> 12, n = t & 4095, yy = n >> 6, xx = n & 63;
    float acc = bdw[c];
    const float* yc = y + (size_t)c * 4096;
#pragma unroll
    for (int ky = 0; ky < 3; ++ky) {
        int ry = yy + ky - 1;
        if ((unsigned)ry < 64u) {
#pragma unroll
            for (int kx = 0; kx < 3; ++kx) {
                int rx = xx + kx - 1;
                if ((unsigned)rx < 64u) acc += wdw[c * 9 + ky * 3 + kx] * yc[ry * 64 + rx];
            }
        }
    }
    dwout[t] = acc;
    dwt[n * 256 + c] = (bf16)acc;
}

// ---------------------------------------------------------------------------
extern "C" void kernel_launch(void* const* d_in, const int* in_sizes, int n_in,
                              void* d_out, int out_size, void* d_ws, size_t ws_size,
                              hipStream_t stream) {
    const float* x   = (const float*)d_in[0];
    const float* wq1 = (const float*)d_in[1];
    const float* wk1 = (const float*)d_in[2];
    const float* wv1 = (const float*)d_in[3];
    const float* wq2 = (const float*)d_in[4];
    const float* wk2 = (const float*)d_in[5];
    const float* wv2 = (const float*)d_in[6];
    const float* wo  = (const float*)d_in[7];
    const float* bo  = (const float*)d_in[8];
    const float* wdw = (const float*)d_in[9];
    const float* bdw = (const float*)d_in[10];
    const float* wg  = (const float*)d_in[11];
    const float* bg  = (const float*)d_in[12];

    char* ws = (char*)d_ws;
    size_t off = 0;
    auto alloc = [&](size_t bytes) {
        char* p = ws + off;
        off += (bytes + 255) & ~(size_t)255;
        return p;
    };
    // persistent
    bf16*  q_buf = (bf16*)alloc((size_t)8 * 4096 * 64 * 2);
    bf16*  k_buf = (bf16*)alloc((size_t)8 * 4096 * 64 * 2);
    bf16*  vT    = (bf16*)alloc((size_t)8 * 64 * 4096 * 2);
    bf16*  o_buf = (bf16*)alloc((size_t)4096 * 512 * 2);
    bf16*  wo_bf = (bf16*)alloc((size_t)256 * 512 * 2);
    bf16*  wg_bf = (bf16*)alloc((size_t)256 * 256 * 2);
    // union region (lifetimes disjoint):
    char* U = ws + off;
    bf16*  xbf = (bf16*)U;
    bf16*  Wq  = (bf16*)(U + (size_t)2 * 1024 * 1024);
    bf16*  Wk  = (bf16*)(U + (size_t)2 * 1024 * 1024 + 262144);
    bf16*  Wv  = (bf16*)(U + (size_t)2 * 1024 * 1024 + 524288);
    bf16*  Opart = (bf16*)U;                                   // 16MB
    float* lpart = (float*)(U + (size_t)16 * 1024 * 1024);     // 512KB
    float* ybuf  = (float*)U;
    float* dwout = (float*)(U + (size_t)4 * 1024 * 1024);
    bf16*  dwt   = (bf16*)(U + (size_t)8 * 1024 * 1024);
    (void)ws_size; (void)in_sizes; (void)n_in; (void)out_size;

    const float QSCALE = 0.125f * 1.4426950408889634f;  // fold 1/sqrt(dk) * log2(e)

    k_pre<<<2560, 256, 0, stream>>>(x, xbf, wq1, wk1, wv1, wq2, wk2, wv2, wo, wg,
                                    Wq, Wk, Wv, wo_bf, wg_bf);
    k_qkv<<<768, 256, 0, stream>>>(xbf, Wq, Wk, Wv, q_buf, k_buf, vT, QSCALE);
    k_attn<<<1024, 256, 0, stream>>>(q_buf, k_buf, vT, Opart, lpart);
    k_combine<<<1024, 256, 0, stream>>>(Opart, lpart, o_buf);
    k_gemm64<2><<<dim3(64, 4), 256, 0, stream>>>(wo_bf, o_buf, 512, ybuf, bo, nullptr);
    k_dw<<<4096, 256, 0, stream>>>(ybuf, wdw, bdw, dwout, dwt);
    k_gemm64<3><<<dim3(64, 4), 256, 0, stream>>>(wg_bf, dwt, 256, d_out, bg, dwout);
}

// Round 16
// 111.610 us; speedup vs baseline: 1.7099x; 1.0264x over previous
//
#include <hip/hip_runtime.h>

typedef __bf16 bf16;
typedef __bf16 bf16x4 __attribute__((ext_vector_type(4)));
typedef __bf16 bf16x8 __attribute__((ext_vector_type(8)));
typedef float f32x4 __attribute__((ext_vector_type(4)));

#define MFMA16(a, b, c) __builtin_amdgcn_mfma_f32_16x16x32_bf16((a), (b), (c), 0, 0, 0)

__device__ inline float fexp2(float x) {
    float r;
    asm("v_exp_f32 %0, %1" : "=v"(r) : "v"(x));
    return r;
}

// ---------------------------------------------------------------------------
// K1: fused pre-pass.  blocks 0-255: transpose x [256][4096] f32 ->
// xt [4096][256] bf16 (LDS-tiled).  blocks 256+: fused weights
// Wq/Wk/Wv = w2 @ w1 [512][256] bf16 + wo/wg -> bf16.
// ---------------------------------------------------------------------------
__global__ void k_pre(const float* __restrict__ x, bf16* __restrict__ xt,
                      const float* __restrict__ wq1, const float* __restrict__ wk1,
                      const float* __restrict__ wv1, const float* __restrict__ wq2,
                      const float* __restrict__ wk2, const float* __restrict__ wv2,
                      const float* __restrict__ wo, const float* __restrict__ wg,
                      bf16* __restrict__ Wq, bf16* __restrict__ Wk, bf16* __restrict__ Wv,
                      bf16* __restrict__ wo_bf, bf16* __restrict__ wg_bf) {
    __shared__ float tile[64][68];
    const int bx = blockIdx.x;
    if (bx < 256) {
        const int t = threadIdx.x;
        const int c0 = (bx & 3) * 64;
        const int n0 = (bx >> 2) * 64;
        {
            const int cr = t >> 4, nc = (t & 15) * 4;
#pragma unroll
            for (int i = 0; i < 4; ++i) {
                const float4 v = *(const float4*)(x + (size_t)(c0 + cr + i * 16) * 4096 + n0 + nc);
                tile[cr + i * 16][nc + 0] = v.x;
                tile[cr + i * 16][nc + 1] = v.y;
                tile[cr + i * 16][nc + 2] = v.z;
                tile[cr + i * 16][nc + 3] = v.w;
            }
        }
        __syncthreads();
        const int n = t >> 2, cc = (t & 3) * 16;
        bf16x8 o0, o1;
#pragma unroll
        for (int j = 0; j < 8; ++j) o0[j] = (bf16)tile[cc + j][n];
#pragma unroll
        for (int j = 0; j < 8; ++j) o1[j] = (bf16)tile[cc + 8 + j][n];
        bf16* dst = xt + (size_t)(n0 + n) * 256 + c0 + cc;
        *(bf16x8*)dst = o0;
        *(bf16x8*)(dst + 8) = o1;
    } else {
        int t = (bx - 256) * 256 + threadIdx.x;
        if (t < 393216) {                       // 3 * 512 * 256
            int which = t >> 17;
            int rem = t & 131071;
            int o = rem >> 8, c = rem & 255;
            const float* w1 = which == 0 ? wq1 : which == 1 ? wk1 : wv1;
            const float* w2 = which == 0 ? wq2 : which == 1 ? wk2 : wv2;
            float acc = 0.f;
#pragma unroll
            for (int j = 0; j < 32; ++j) acc += w2[o * 32 + j] * w1[j * 256 + c];
            bf16* W = which == 0 ? Wq : which == 1 ? Wk : Wv;
            W[o * 256 + c] = (bf16)acc;
        } else if (t < 524288) {                // wo: 256*512
            int idx = t - 393216;
            wo_bf[idx] = (bf16)wo[idx];
        } else if (t < 589824) {                // wg: 256*256
            int idx = t - 524288;
            wg_bf[idx] = (bf16)wg[idx];
        }
    }
}

// ---------------------------------------------------------------------------
// GEMM-NT body (tile 128x64): C[i][j] = sum_k A[i][k]*B[j][k].
// MODE 0: -> bf16 [j>>6][i][j&63] with scale; MODE 1: -> bf16 [i][j].
// ---------------------------------------------------------------------------
template <int MODE>
__device__ __forceinline__ void gemm_body(const bf16* __restrict__ A, const bf16* __restrict__ B,
                                          int K, float scale, void* __restrict__ outp,
                                          int bx, int by) {
    const int lane = threadIdx.x & 63;
    const int w = threadIdx.x >> 6;
    const int i0 = by * 128 + w * 32;
    const int j0 = bx * 64;
    const int lrow = lane & 15;
    const int lk = (lane >> 4) * 8;

    f32x4 acc[2][4];
#pragma unroll
    for (int a = 0; a < 2; ++a)
#pragma unroll
        for (int b = 0; b < 4; ++b) acc[a][b] = (f32x4){0.f, 0.f, 0.f, 0.f};

    for (int k0 = 0; k0 < K; k0 += 32) {
        bf16x8 af[2], bfr[4];
#pragma unroll
        for (int qs = 0; qs < 2; ++qs)
            af[qs] = *(const bf16x8*)(A + (size_t)(i0 + qs * 16 + lrow) * K + k0 + lk);
#pragma unroll
        for (int js = 0; js < 4; ++js)
            bfr[js] = *(const bf16x8*)(B + (size_t)(j0 + js * 16 + lrow) * K + k0 + lk);
#pragma unroll
        for (int qs = 0; qs < 2; ++qs)
#pragma unroll
            for (int js = 0; js < 4; ++js)
                acc[qs][js] = MFMA16(af[qs], bfr[js], acc[qs][js]);
    }

    const int rbase = (lane >> 4) * 4;
#pragma unroll
    for (int qs = 0; qs < 2; ++qs)
#pragma unroll
        for (int js = 0; js < 4; ++js)
#pragma unroll
            for (int r = 0; r < 4; ++r) {
                int i = i0 + qs * 16 + rbase + r;
                int j = j0 + js * 16 + lrow;
                float v = acc[qs][js][r];
                if (MODE == 0) {
                    ((bf16*)outp)[(size_t)(j >> 6) * (4096 * 64) + (size_t)i * 64 + (j & 63)] =
                        (bf16)(v * scale);
                } else {
                    ((bf16*)outp)[(size_t)i * 4096 + j] = (bf16)v;
                }
            }
}

// ---------------------------------------------------------------------------
// GEMM-NT (tile 64x64, 256-block fill for small outputs):
// MODE 2: -> f32 [i][j] + bias[i]; MODE 3: -> f32 mul*sigmoid(acc+bias).
// ---------------------------------------------------------------------------
template <int MODE>
__launch_bounds__(256)
__global__ void k_gemm64(const bf16* __restrict__ A, const bf16* __restrict__ B,
                         int K, void* __restrict__ outp,
                         const float* __restrict__ bias, const float* __restrict__ mul) {
    const int lane = threadIdx.x & 63;
    const int w = threadIdx.x >> 6;
    const int i0 = blockIdx.y * 64 + w * 16;
    const int j0 = blockIdx.x * 64;
    const int lrow = lane & 15;
    const int lk = (lane >> 4) * 8;

    f32x4 acc[4];
#pragma unroll
    for (int b = 0; b < 4; ++b) acc[b] = (f32x4){0.f, 0.f, 0.f, 0.f};

    for (int k0 = 0; k0 < K; k0 += 32) {
        bf16x8 af = *(const bf16x8*)(A + (size_t)(i0 + lrow) * K + k0 + lk);
        bf16x8 bfr[4];
#pragma unroll
        for (int js = 0; js < 4; ++js)
            bfr[js] = *(const bf16x8*)(B + (size_t)(j0 + js * 16 + lrow) * K + k0 + lk);
#pragma unroll
        for (int js = 0; js < 4; ++js)
            acc[js] = MFMA16(af, bfr[js], acc[js]);
    }

    const int rbase = (lane >> 4) * 4;
#pragma unroll
    for (int js = 0; js < 4; ++js)
#pragma unroll
        for (int r = 0; r < 4; ++r) {
            int i = i0 + rbase + r;
            int j = j0 + js * 16 + lrow;
            float v = acc[js][r];
            if (MODE == 2) {
                ((float*)outp)[(size_t)i * 4096 + j] = v + bias[i];
            } else {
                float g2 = v + bias[i];
                float sg = 1.f / (1.f + __expf(-g2));
                ((float*)outp)[(size_t)i * 4096 + j] = mul[(size_t)i * 4096 + j] * sg;
            }
        }
}

// ---------------------------------------------------------------------------
// K3: merged Q/K/V projection -- one 768-block launch.
// ---------------------------------------------------------------------------
__launch_bounds__(256)
__global__ void k_qkv(const bf16* __restrict__ xbf, const bf16* __restrict__ Wq,
                      const bf16* __restrict__ Wk, const bf16* __restrict__ Wv,
                      bf16* __restrict__ q_buf, bf16* __restrict__ k_buf,
                      bf16* __restrict__ vT, float qscale) {
    const int b = blockIdx.x;
    if (b < 256) {
        gemm_body<0>(xbf, Wq, 256, qscale, q_buf, b & 7, b >> 3);
    } else if (b < 512) {
        const int bb = b - 256;
        gemm_body<0>(xbf, Wk, 256, 1.0f, k_buf, bb & 7, bb >> 3);
    } else {
        const int bb = b - 512;
        gemm_body<1>(Wv, xbf, 256, 1.0f, vT, bb & 63, bb >> 6);
    }
}

// ---------------------------------------------------------------------------
// K4: flash attention, KV-split S=4, static-max softmax (exp2, shift=0).
// R16 delta: first-ks MFMA accumulates into a loop-invariant ZERO vector
// (s = mfma(ak, bq, zero4)) -- kills the 32 per-tile v_mov zero-inits that
// were ~30% of non-exp VALU work (VALUBusy 44% was the top pipe).
// Everything else: proven R15 structure (K/V fragments read once, shared
// across qs; ones-MFMA row-sum; lambda-free; reg-staged prefetch).
// grid = 1024 (split<<8 | h<<5 | qt), block = 256 (4 waves x 32 q-rows).
// ---------------------------------------------------------------------------
__launch_bounds__(256)
__global__ void k_attn(const bf16* __restrict__ q, const bf16* __restrict__ k,
                       const bf16* __restrict__ vT, bf16* __restrict__ Opart,
                       float* __restrict__ lpart) {
    __shared__ char kvlds[16384];           // K [64 rows][128B] at 0, V at 8192
    __shared__ char plds[4][4096];          // per-wave P [32 rows][128B]
    const int tid = threadIdx.x;
    const int lane = tid & 63;
    const int w = tid >> 6;
    const int split = blockIdx.x >> 8;
    const int h = (blockIdx.x >> 5) & 7;
    const int qt = blockIdx.x & 31;
    const int qbase = qt * 128 + w * 32;
    const int lrow = lane & 15;
    const int g = lane >> 4;
    const int swzr = (lrow & 7) << 4;       // same for row lrow and row 16+lrow

    const bf16* qh = q + (size_t)h * 4096 * 64;
    const bf16* kh = k + (size_t)h * 4096 * 64;
    const bf16* vh = vT + (size_t)h * 64 * 4096;
    char* myp = plds[w];
    const char* Kl = kvlds;
    const char* Vl = kvlds + 8192;

    // staging geometry: threads 0-127 stage K (8KB), 128-255 stage V (8KB)
    const int isV = tid >> 7;
    const int srow = (tid & 127) >> 1;
    const int shalf = tid & 1;
    const int swzs = (srow & 7) << 4;
    char* ldst = kvlds + isV * 8192 + srow * 128;
    const bf16* sbase = isV ? (vh + (size_t)srow * 4096 + split * 1024 + shalf * 32)
                            : (kh + ((size_t)split * 1024 + srow) * 64 + shalf * 32);
    const size_t sstep = isV ? 64 : 64 * 64;   // elements per tile step

    // Q as B-fragments (col = q-row = lane&15)
    bf16x8 bq[2][2];
#pragma unroll
    for (int qs = 0; qs < 2; ++qs)
#pragma unroll
        for (int ks = 0; ks < 2; ++ks)
            bq[qs][ks] = *(const bf16x8*)(qh + (size_t)(qbase + qs * 16 + lrow) * 64 +
                                          ks * 32 + g * 8);

    f32x4 accO[2][4];
    f32x4 l_acc[2];
#pragma unroll
    for (int qs = 0; qs < 2; ++qs) {
#pragma unroll
        for (int ds = 0; ds < 4; ++ds) accO[qs][ds] = (f32x4){0.f, 0.f, 0.f, 0.f};
        l_acc[qs] = (f32x4){0.f, 0.f, 0.f, 0.f};
    }
    const f32x4 zero4 = (f32x4){0.f, 0.f, 0.f, 0.f};   // loop-invariant C=0
    bf16x8 ones;
#pragma unroll
    for (int i = 0; i < 8; ++i) ones[i] = (bf16)1.0f;

    // prologue: stage tile 0 into regs
    uint4 r0, r1, r2, r3;
    {
        const bf16* p = sbase;
        r0 = *(const uint4*)(p);
        r1 = *(const uint4*)(p + 8);
        r2 = *(const uint4*)(p + 16);
        r3 = *(const uint4*)(p + 24);
    }

    for (int t = 0; t < 16; ++t) {
        // ---- write staged tile to LDS (XOR-swizzled rows) ----
        *(uint4*)(ldst + ((shalf * 64 + 0) ^ swzs)) = r0;
        *(uint4*)(ldst + ((shalf * 64 + 16) ^ swzs)) = r1;
        *(uint4*)(ldst + ((shalf * 64 + 32) ^ swzs)) = r2;
        *(uint4*)(ldst + ((shalf * 64 + 48) ^ swzs)) = r3;
        // ---- prefetch next tile into the same regs ----
        if (t < 15) {
            const bf16* p = sbase + (size_t)(t + 1) * sstep;
            r0 = *(const uint4*)(p);
            r1 = *(const uint4*)(p + 8);
            r2 = *(const uint4*)(p + 16);
            r3 = *(const uint4*)(p + 24);
        }
        __syncthreads();

        // ---- S^T for BOTH qs halves; K fragments read once.
        //      ks=0 accumulates into the invariant zero4 (no per-tile movs).
        f32x4 s[2][4];
        __builtin_amdgcn_s_setprio(1);
        {
            bf16x8 ak[4];
#pragma unroll
            for (int js = 0; js < 4; ++js)
                ak[js] = *(const bf16x8*)(Kl + (js * 16 + lrow) * 128 + ((g * 16) ^ swzr));
#pragma unroll
            for (int qs = 0; qs < 2; ++qs)
#pragma unroll
                for (int js = 0; js < 4; ++js)
                    s[qs][js] = MFMA16(ak[js], bq[qs][0], zero4);
        }
        {
            bf16x8 ak[4];
#pragma unroll
            for (int js = 0; js < 4; ++js)
                ak[js] = *(const bf16x8*)(Kl + (js * 16 + lrow) * 128 + ((64 + g * 16) ^ swzr));
#pragma unroll
            for (int qs = 0; qs < 2; ++qs)
#pragma unroll
                for (int js = 0; js < 4; ++js)
                    s[qs][js] = MFMA16(ak[js], bq[qs][1], s[qs][js]);
        }
        __builtin_amdgcn_s_setprio(0);

        // ---- P = exp2(s) -> per-wave LDS (both qs) ----
#pragma unroll
        for (int qs = 0; qs < 2; ++qs) {
            const int qrow = qs * 16 + lrow;
#pragma unroll
            for (int js = 0; js < 4; ++js) {
                bf16x4 pk;
#pragma unroll
                for (int r = 0; r < 4; ++r) pk[r] = (bf16)fexp2(s[qs][js][r]);
                *(bf16x4*)(myp + ((qrow * 128 + js * 32 + g * 8) ^ swzr)) = pk;
            }
        }

        // ---- O += P V ; l += P @ ones.  V fragments read once ----
        __builtin_amdgcn_s_setprio(1);
#pragma unroll
        for (int ks2 = 0; ks2 < 2; ++ks2) {
            bf16x8 bv[4];
#pragma unroll
            for (int ds = 0; ds < 4; ++ds)
                bv[ds] = *(const bf16x8*)(Vl + (ds * 16 + lrow) * 128 +
                                          ((ks2 * 64 + g * 16) ^ swzr));
            bf16x8 ap0 = *(const bf16x8*)(myp + ((lrow * 128 + ks2 * 64 + g * 16) ^ swzr));
            bf16x8 ap1 = *(const bf16x8*)(myp + (((16 + lrow) * 128 + ks2 * 64 + g * 16) ^ swzr));
#pragma unroll
            for (int ds = 0; ds < 4; ++ds)
                accO[0][ds] = MFMA16(ap0, bv[ds], accO[0][ds]);
            l_acc[0] = MFMA16(ap0, ones, l_acc[0]);
#pragma unroll
            for (int ds = 0; ds < 4; ++ds)
                accO[1][ds] = MFMA16(ap1, bv[ds], accO[1][ds]);
            l_acc[1] = MFMA16(ap1, ones, l_acc[1]);
        }
        __builtin_amdgcn_s_setprio(0);
        __syncthreads();   // all waves done with this KV tile before overwrite
    }

    // ---- store partials (unnormalized) ----
#pragma unroll
    for (int qs = 0; qs < 2; ++qs)
#pragma unroll
        for (int ds = 0; ds < 4; ++ds)
#pragma unroll
            for (int r = 0; r < 4; ++r) {
                const int n = qbase + qs * 16 + 4 * g + r;
                Opart[((size_t)split * 4096 + n) * 512 + h * 64 + ds * 16 + lrow] =
                    (bf16)accO[qs][ds][r];
            }
    if (lrow == 0) {
#pragma unroll
        for (int qs = 0; qs < 2; ++qs)
#pragma unroll
            for (int r = 0; r < 4; ++r)
                lpart[((size_t)split * 8 + h) * 4096 + qbase + qs * 16 + 4 * g + r] =
                    l_acc[qs][r];
    }
}

// ---------------------------------------------------------------------------
// K5: combine partials -> o_buf bf16 [4096][512]
// ---------------------------------------------------------------------------
__global__ void k_combine(const bf16* __restrict__ Opart, const float* __restrict__ lpart,
                          bf16* __restrict__ o) {
    const int tid = blockIdx.x * 256 + threadIdx.x;   // 262144
    const int n = tid >> 6;
    const int c8 = (tid & 63) * 8;
    const int h = c8 >> 6;
    float acc[8] = {0, 0, 0, 0, 0, 0, 0, 0};
    float l = 0.f;
#pragma unroll
    for (int s = 0; s < 4; ++s) {
        const bf16x8 v = *(const bf16x8*)(Opart + ((size_t)s * 4096 + n) * 512 + c8);
#pragma unroll
        for (int j = 0; j < 8; ++j) acc[j] += (float)v[j];
        l += lpart[((size_t)s * 8 + h) * 4096 + n];
    }
    const float inv = 1.f / l;
    bf16x8 ov;
#pragma unroll
    for (int j = 0; j < 8; ++j) ov[j] = (bf16)(acc[j] * inv);
    *(bf16x8*)(o + (size_t)n * 512 + c8) = ov;
}

// ---------------------------------------------------------------------------
// K6: depthwise 3x3 conv (SAME), vectorized: 4 outputs/thread via float4.
// 256K threads (was 1M scalar).  dwout f32 [c][n] (float4 store) and
// dwt bf16 [n][256] for the gate GEMM.
// ---------------------------------------------------------------------------
__global__ void k_dw(const float* __restrict__ y, const float* __restrict__ wdw,
                     const float* __restrict__ bdw, float* __restrict__ dwout,
                     bf16* __restrict__ dwt) {
    int t = blockIdx.x * 256 + threadIdx.x;   // 262144
    int c = t >> 10, rem = t & 1023;
    int yy = rem >> 4, xx0 = (rem & 15) * 4;
    const float* yc = y + (size_t)c * 4096;
    float w0r[3], w1r[3], w2r[3];
#pragma unroll
    for (int ky = 0; ky < 3; ++ky) {
        w0r[ky] = wdw[c * 9 + ky * 3 + 0];
        w1r[ky] = wdw[c * 9 + ky * 3 + 1];
        w2r[ky] = wdw[c * 9 + ky * 3 + 2];
    }
    float b = bdw[c];
    float acc0 = b, acc1 = b, acc2 = b, acc3 = b;
#pragma unroll
    for (int ky = 0; ky < 3; ++ky) {
        int ry = yy + ky - 1;
        if ((unsigned)ry < 64u) {
            const float* row = yc + ry * 64 + xx0;
            float4 v = *(const float4*)row;
            float left = (xx0 > 0) ? row[-1] : 0.f;
            float right = (xx0 < 60) ? row[4] : 0.f;
            acc0 += w0r[ky] * left + w1r[ky] * v.x + w2r[ky] * v.y;
            acc1 += w0r[ky] * v.x + w1r[ky] * v.y + w2r[ky] * v.z;
            acc2 += w0r[ky] * v.y + w1r[ky] * v.z + w2r[ky] * v.w;
            acc3 += w0r[ky] * v.z + w1r[ky] * v.w + w2r[ky] * right;
        }
    }
    const int n = yy * 64 + xx0;
    *(float4*)(dwout + (size_t)c * 4096 + n) = make_float4(acc0, acc1, acc2, acc3);
    dwt[(size_t)(n + 0) * 256 + c] = (bf16)acc0;
    dwt[(size_t)(n + 1) * 256 + c] = (bf16)acc1;
    dwt[(size_t)(n + 2) * 256 + c] = (bf16)acc2;
    dwt[(size_t)(n + 3) * 256 + c] = (bf16)acc3;
}

// ---------------------------------------------------------------------------
extern "C" void kernel_launch(void* const* d_in, const int* in_sizes, int n_in,
                              void* d_out, int out_size, void* d_ws, size_t ws_size,
                              hipStream_t stream) {
    const float* x   = (const float*)d_in[0];
    const float* wq1 = (const float*)d_in[1];
    const float* wk1 = (const float*)d_in[2];
    const float* wv1 = (const float*)d_in[3];
    const float* wq2 = (const float*)d_in[4];
    const float* wk2 = (const float*)d_in[5];
    const float* wv2 = (const float*)d_in[6];
    const float* wo  = (const float*)d_in[7];
    const float* bo  = (const float*)d_in[8];
    const float* wdw = (const float*)d_in[9];
    const float* bdw = (const float*)d_in[10];
    const float* wg  = (const float*)d_in[11];
    const float* bg  = (const float*)d_in[12];

    char* ws = (char*)d_ws;
    size_t off = 0;
    auto alloc = [&](size_t bytes) {
        char* p = ws + off;
        off += (bytes + 255) & ~(size_t)255;
        return p;
    };
    // persistent
    bf16*  q_buf = (bf16*)alloc((size_t)8 * 4096 * 64 * 2);
    bf16*  k_buf = (bf16*)alloc((size_t)8 * 4096 * 64 * 2);
    bf16*  vT    = (bf16*)alloc((size_t)8 * 64 * 4096 * 2);
    bf16*  o_buf = (bf16*)alloc((size_t)4096 * 512 * 2);
    bf16*  wo_bf = (bf16*)alloc((size_t)256 * 512 * 2);
    bf16*  wg_bf = (bf16*)alloc((size_t)256 * 256 * 2);
    // union region (lifetimes disjoint):
    char* U = ws + off;
    bf16*  xbf = (bf16*)U;
    bf16*  Wq  = (bf16*)(U + (size_t)2 * 1024 * 1024);
    bf16*  Wk  = (bf16*)(U + (size_t)2 * 1024 * 1024 + 262144);
    bf16*  Wv  = (bf16*)(U + (size_t)2 * 1024 * 1024 + 524288);
    bf16*  Opart = (bf16*)U;                                   // 16MB
    float* lpart = (float*)(U + (size_t)16 * 1024 * 1024);     // 512KB
    float* ybuf  = (float*)U;
    float* dwout = (float*)(U + (size_t)4 * 1024 * 1024);
    bf16*  dwt   = (bf16*)(U + (size_t)8 * 1024 * 1024);
    (void)ws_size; (void)in_sizes; (void)n_in; (void)out_size;

    const float QSCALE = 0.125f * 1.4426950408889634f;  // fold 1/sqrt(dk) * log2(e)

    k_pre<<<2560, 256, 0, stream>>>(x, xbf, wq1, wk1, wv1, wq2, wk2, wv2, wo, wg,
                                    Wq, Wk, Wv, wo_bf, wg_bf);
    k_qkv<<<768, 256, 0, stream>>>(xbf, Wq, Wk, Wv, q_buf, k_buf, vT, QSCALE);
    k_attn<<<1024, 256, 0, stream>>>(q_buf, k_buf, vT, Opart, lpart);
    k_combine<<<1024, 256, 0, stream>>>(Opart, lpart, o_buf);
    k_gemm64<2><<<dim3(64, 4), 256, 0, stream>>>(wo_bf, o_buf, 512, ybuf, bo, nullptr);
    k_dw<<<1024, 256, 0, stream>>>(ybuf, wdw, bdw, dwout, dwt);
    k_gemm64<3><<<dim3(64, 4), 256, 0, stream>>>(wg_bf, dwt, 256, d_out, bg, dwout);
}